// Round 5
// baseline (267.014 us; speedup 1.0000x reference)
//
#include <hip/hip_runtime.h>
#include <hip/hip_bf16.h>
#include <math.h>

#define SS 8
#define NN 32
#define DD 64
#define NP 496   // 32*31/2
#define LDA 68   // padded row stride (floats) for sAi/sBj; 272B (16B-aligned)

typedef short v8s __attribute__((ext_vector_type(8)));   // 8 bf16 (4 VGPRs)
typedef float v4f __attribute__((ext_vector_type(4)));   // MFMA C/D frag
typedef float f2  __attribute__((ext_vector_type(2)));   // packed fp32 pair (VOP3P)

union FragU { uint4 u; v8s s; };
union Q2    { float4 q; f2 h[2]; };

static __device__ __forceinline__ f2 f2m(float a, float b) { f2 r; r.x = a; r.y = b; return r; }
static __device__ __forceinline__ f2 splat2(float s) { f2 r; r.x = s; r.y = s; return r; }
static __device__ __forceinline__ f2 pk_fma(f2 a, f2 b, f2 c) {
#if __has_builtin(__builtin_elementwise_fma)
    return __builtin_elementwise_fma(a, b, c);    // -> v_pk_fma_f32
#else
    return f2m(fmaf(a.x, b.x, c.x), fmaf(a.y, b.y, c.y));
#endif
}

__device__ __forceinline__ float wrap_pi(float d) {
    return fmaf(-6.28318530717958647692f, rintf(d * 0.15915494309189533577f), d);
}
// sigmoid via hw rcp (avoids the ~10-inst v_div refinement chain; 1e-7 rel err)
__device__ __forceinline__ float sigmoid_(float x) {
    return __builtin_amdgcn_rcpf(1.0f + __expf(-x));
}
// Sign-free packed GELU. erf via A&S 7.1.25-style rational (|eps|<=5e-4, no
// exp, 1 rcp/elem). gelu(x) = (0.5x + a) - (a*t^2)*t^2, a = 0.5|x|.
__device__ __forceinline__ f2 gelu2(f2 x) {
#if __has_builtin(__builtin_elementwise_max)
    f2 ax = __builtin_elementwise_max(x, -x);
#else
    f2 ax = f2m(fabsf(x.x), fabsf(x.y));
#endif
    f2 az = ax * splat2(0.70710678118654752440f);
    f2 d = pk_fma(splat2(0.078108f), az, splat2(0.000972f));
    d = pk_fma(d, az, splat2(0.230389f));
    d = pk_fma(d, az, splat2(0.278393f));
    d = pk_fma(d, az, splat2(1.0f));
    f2 t = f2m(__builtin_amdgcn_rcpf(d.x), __builtin_amdgcn_rcpf(d.y));
    f2 t2 = t * t;
    f2 a = ax * splat2(0.5f);
    f2 base = pk_fma(x, splat2(0.5f), a);
    f2 u = a * t2;
    return pk_fma(-u, t2, base);
}
// fp32 pair -> packed bf16 (RNE). HW path: v_cvt_pk_bf16_f32 on gfx950.
__device__ __forceinline__ unsigned int pack_bf16_rne(float x0, float x1) {
    union { __hip_bfloat162 h2; unsigned int u; } cv;
    float2 f; f.x = x0; f.y = x1;
    cv.h2 = __float22bfloat162_rn(f);
    return cv.u;
}
// Sum across each 16-lane DPP row via row_ror 8/4/2/1 (rotation butterfly:
// every lane ends with the full row sum, direction-agnostic). VALU pipe.
__device__ __forceinline__ float row_reduce16(float x) {
    int v;
    v = __builtin_amdgcn_update_dpp(0, __float_as_int(x), 0x128, 0xf, 0xf, false);
    x += __int_as_float(v);
    v = __builtin_amdgcn_update_dpp(0, __float_as_int(x), 0x124, 0xf, 0xf, false);
    x += __int_as_float(v);
    v = __builtin_amdgcn_update_dpp(0, __float_as_int(x), 0x122, 0xf, 0xf, false);
    x += __int_as_float(v);
    v = __builtin_amdgcn_update_dpp(0, __float_as_int(x), 0x121, 0xf, 0xf, false);
    x += __int_as_float(v);
    return x;
}
__device__ __forceinline__ uint4 build_w2_frag(const float* __restrict__ W2,
                                               int kb, int col) {
    uint4 pk;
    pk.x = pack_bf16_rne(W2[(kb + 0) * 32 + col], W2[(kb + 1) * 32 + col]);
    pk.y = pack_bf16_rne(W2[(kb + 2) * 32 + col], W2[(kb + 3) * 32 + col]);
    pk.z = pack_bf16_rne(W2[(kb + 4) * 32 + col], W2[(kb + 5) * 32 + col]);
    pk.w = pack_bf16_rne(W2[(kb + 6) * 32 + col], W2[(kb + 7) * 32 + col]);
    return pk;
}

// History: R2 proved launch_bounds(256,4) caps VGPR at 64 -> scratch spill
// (FETCH 17->101MB, dur 89->138us). R4 proved block=512 diverges post-timing
// (unexplained -> axis abandoned). R0-R3: static resources (LDS 39.9-42KB,
// VGPR 52-84) never move dur off 89.5us; VALUBusy 56% at ~2.3 waves/SIMD ->
// latency-bound. This version: two-tile ILP per wave-round (4 rounds x 2
// tiles), same 256-thread structure, same numerics per tile.
__global__ __launch_bounds__(256, 2) void edge_kernel(
    const float* __restrict__ cel,    // (B,S,N,D)
    const float* __restrict__ theta,  // (B,N)
    const float* __restrict__ phi,
    const float* __restrict__ vel,
    const float* __restrict__ rad,
    const float* __restrict__ lon,
    const float* __restrict__ W1,     // (134,64)
    const float* __restrict__ b1,     // (64)
    const float* __restrict__ W2,     // (64,32)
    const float* __restrict__ b2,     // (32)
    const float* __restrict__ W3,     // (32)
    const float* __restrict__ b3,     // (1)
    const float* __restrict__ pw,     // (6)
    float* __restrict__ out)          // (B,N,N)
{
    __shared__ __align__(16) float sAi[NN * LDA];     // fi@W1[0:64] + b1
    __shared__ __align__(16) float sBj[NN * LDA];     // fj@W1[64:128]
    __shared__ __align__(16) float sW1s[6 * 64];      // W1 rows 128..133
    __shared__ float sAdj[1024];
    __shared__ __align__(16) float sScal[NP * 8];     // f32, stride 8: {td,pd,vd,rr}|{ld,pr,gate,-}
    __shared__ unsigned char sI[NP], sJ[NP];

    const int b = blockIdx.x;
    const int t = threadIdx.x;
    const int ml = t & 15;            // frag row-within-tile / C col
    const int ql = (t >> 4) & 3;      // frag k-quad / C row-quad (== lane>>4)
    const int wv = t >> 6;            // wave id 0..3
    const int kA = ql * 8;            // this lane's ks0 k-base

    // ---- B-fragments of W2 straight from global (per-thread, no LDS) ----
    FragU f00, f01, f10, f11;
    f00.u = build_w2_frag(W2, 0 * 32 + kA, 0 * 16 + ml);
    f01.u = build_w2_frag(W2, 1 * 32 + kA, 0 * 16 + ml);
    f10.u = build_w2_frag(W2, 0 * 32 + kA, 1 * 16 + ml);
    f11.u = build_w2_frag(W2, 1 * 32 + kA, 1 * 16 + ml);
    const float b2v0 = b2[ml], b2v1 = b2[16 + ml];
    const float w3v0 = W3[ml], w3v1 = W3[16 + ml];
    const float b3s  = b3[0];

    // ---- staging ----
    if (t < 31) {  // triu pair table
        int off = t * 31 - (t * (t - 1)) / 2;
        for (int j = t + 1; j < 32; ++j) {
            sI[off] = (unsigned char)t;
            sJ[off] = (unsigned char)j;
            ++off;
        }
    }
    for (int idx = t; idx < 1024; idx += 256) sAdj[idx] = 0.0f;
    for (int idx = t; idx < 384; idx += 256) sW1s[idx] = W1[128 * 64 + idx];
    __syncthreads();   // barrier 1

    // ---- per-pair scalars + gate (node attrs straight from global: tiny,
    //      L1-broadcast). Gate packed into sScal chunk1 slot 2. ----
    for (int p = t; p < NP; p += 256) {
        const int i = sI[p], j = sJ[p];
        const float td = wrap_pi(theta[b * NN + i] - theta[b * NN + j]);
        const float pd = wrap_pi(phi[b * NN + i] - phi[b * NN + j]);
        const float vd = vel[b * NN + i] - vel[b * NN + j];
        const float rr = rad[b * NN + i] * __builtin_amdgcn_rcpf(rad[b * NN + j] + 1e-8f);
        const float ld = wrap_pi(lon[b * NN + i] - lon[b * NN + j]);
        const float pr = __cosf(td) * __cosf(pd);
        const float pf = fabsf(td) * pw[0] + fabsf(pd) * pw[1]
                       + fabsf(vd) * pw[2] + fabsf(rr - 1.0f) * pw[3]
                       + fabsf(ld) * pw[4] + fabsf(pr) * pw[5];
        const int sw = (p >> 2) & 1;   // chunk XOR-swizzle bit
        float4* c0 = (float4*)&sScal[p * 8 + (sw << 2)];
        float4* c1 = (float4*)&sScal[p * 8 + ((sw ^ 1) << 2)];
        *c0 = float4{td, pd, vd, rr};
        *c1 = float4{ld, pr, sigmoid_(pf), 0.0f};
    }

    // ---- phase A: node projections (packed fp32 VALU) ----
    {
        const int col = t & 63;
        const int w   = __builtin_amdgcn_readfirstlane(t >> 6);
        const float* fbase = cel + ((size_t)b * SS + (SS - 1)) * (NN * DD);
        f2 accA[8], accB[8];
        #pragma unroll
        for (int m = 0; m < 8; ++m) { accA[m] = splat2(0.0f); accB[m] = splat2(0.0f); }
        for (int k4 = 0; k4 < 64; k4 += 4) {
            const f2 wa01 = f2m(W1[(k4 + 0) * 64 + col], W1[(k4 + 1) * 64 + col]);
            const f2 wa23 = f2m(W1[(k4 + 2) * 64 + col], W1[(k4 + 3) * 64 + col]);
            const f2 wb01 = f2m(W1[(k4 + 64) * 64 + col], W1[(k4 + 65) * 64 + col]);
            const f2 wb23 = f2m(W1[(k4 + 66) * 64 + col], W1[(k4 + 67) * 64 + col]);
            #pragma unroll
            for (int m = 0; m < 8; ++m) {
                const float4 fv = *(const float4*)&fbase[(w + 4 * m) * 64 + k4]; // s_load_dwordx4
                accA[m] = pk_fma(f2m(fv.x, fv.y), wa01, accA[m]);
                accA[m] = pk_fma(f2m(fv.z, fv.w), wa23, accA[m]);
                accB[m] = pk_fma(f2m(fv.x, fv.y), wb01, accB[m]);
                accB[m] = pk_fma(f2m(fv.z, fv.w), wb23, accB[m]);
            }
        }
        const float b1c = b1[col];
        #pragma unroll
        for (int m = 0; m < 8; ++m) {
            sAi[(w + 4 * m) * LDA + col] = accA[m].x + accA[m].y + b1c;
            sBj[(w + 4 * m) * LDA + col] = accB[m].x + accB[m].y;
        }
    }
    __syncthreads();   // barrier 2

    // ---- hoist BOTH W1s halves for this lane (round-invariant). ----
    f2 w1f[6][8];
    #pragma unroll
    for (int s = 0; s < 6; ++s) {
        Q2 u0, u1, u2, u3;
        u0.q = *(const float4*)&sW1s[s * 64 + kA];
        u1.q = *(const float4*)&sW1s[s * 64 + kA + 4];
        u2.q = *(const float4*)&sW1s[s * 64 + 32 + kA];
        u3.q = *(const float4*)&sW1s[s * 64 + 36 + kA];
        w1f[s][0] = u0.h[0]; w1f[s][1] = u0.h[1];
        w1f[s][2] = u1.h[0]; w1f[s][3] = u1.h[1];
        w1f[s][4] = u2.h[0]; w1f[s][5] = u2.h[1];
        w1f[s][6] = u3.h[0]; w1f[s][7] = u3.h[1];
    }

    // ---- main loop: TWO 16-pair m-tiles per wave-round (ILP pipelining),
    //      4 rounds, ZERO barriers. Tile1 of (r=3,wv=3) would be 31: clamp
    //      its compute to tile 30 (in-bounds, deterministic) and guard the
    //      sAdj write (wave-uniform) so tile 30 is written exactly once. ----
    #pragma clang loop unroll(disable)
    for (int r = 0; r < 4; ++r) {
        const int mtl0 = r * 8 + wv;               // 0..27: always valid
        const int mtl1 = mtl0 + 4;                 // 4..31
        const bool has1 = (mtl1 < 31);             // wave-uniform
        const int mtl1c = has1 ? mtl1 : 30;

        // ---- per-tile scalars / row pointers ----
        const int p0 = mtl0 * 16 + ml;
        const int p1 = mtl1c * 16 + ml;
        const int i0 = sI[p0], j0 = sJ[p0];
        const int i1 = sI[p1], j1 = sJ[p1];
        const int sw0 = (p0 >> 2) & 1;
        const int sw1 = (p1 >> 2) & 1;
        Q2 S00, S01, S10, S11;
        S00.q = *(const float4*)&sScal[p0 * 8 + (sw0 << 2)];
        S01.q = *(const float4*)&sScal[p0 * 8 + ((sw0 ^ 1) << 2)];
        S10.q = *(const float4*)&sScal[p1 * 8 + (sw1 << 2)];
        S11.q = *(const float4*)&sScal[p1 * 8 + ((sw1 ^ 1) << 2)];
        const float sc0[6] = {S00.q.x, S00.q.y, S00.q.z, S00.q.w, S01.q.x, S01.q.y};
        const float sc1[6] = {S10.q.x, S10.q.y, S10.q.z, S10.q.w, S11.q.x, S11.q.y};
        const float* Ar0 = &sAi[i0 * LDA];
        const float* Br0 = &sBj[j0 * LDA];
        const float* Ar1 = &sAi[i1 * LDA];
        const float* Br1 = &sBj[j1 * LDA];

        // ---- tile0 fragments ----
        FragU fa0_0, fa1_0;
        {
            Q2 P0, P1, Q0, Q1;
            P0.q = *(const float4*)(Ar0 + kA);
            P1.q = *(const float4*)(Ar0 + kA + 4);
            Q0.q = *(const float4*)(Br0 + kA);
            Q1.q = *(const float4*)(Br0 + kA + 4);
            f2 v[4] = {P0.h[0] + Q0.h[0], P0.h[1] + Q0.h[1],
                       P1.h[0] + Q1.h[0], P1.h[1] + Q1.h[1]};
            #pragma unroll
            for (int s = 0; s < 6; ++s) {
                const f2 scs = splat2(sc0[s]);
                #pragma unroll
                for (int c = 0; c < 4; ++c)
                    v[c] = pk_fma(scs, w1f[s][c], v[c]);
            }
            #pragma unroll
            for (int c = 0; c < 4; ++c) v[c] = gelu2(v[c]);
            fa0_0.u.x = pack_bf16_rne(v[0].x, v[0].y);
            fa0_0.u.y = pack_bf16_rne(v[1].x, v[1].y);
            fa0_0.u.z = pack_bf16_rne(v[2].x, v[2].y);
            fa0_0.u.w = pack_bf16_rne(v[3].x, v[3].y);
        }
        {
            Q2 P2, P3, Qv2, Q3;
            P2.q  = *(const float4*)(Ar0 + 32 + kA);
            P3.q  = *(const float4*)(Ar0 + 36 + kA);
            Qv2.q = *(const float4*)(Br0 + 32 + kA);
            Q3.q  = *(const float4*)(Br0 + 36 + kA);
            f2 y[4] = {P2.h[0] + Qv2.h[0], P2.h[1] + Qv2.h[1],
                       P3.h[0] + Q3.h[0],  P3.h[1] + Q3.h[1]};
            #pragma unroll
            for (int s = 0; s < 6; ++s) {
                const f2 scs = splat2(sc0[s]);
                #pragma unroll
                for (int c = 0; c < 4; ++c)
                    y[c] = pk_fma(scs, w1f[s][4 + c], y[c]);
            }
            #pragma unroll
            for (int c = 0; c < 4; ++c) y[c] = gelu2(y[c]);
            fa1_0.u.x = pack_bf16_rne(y[0].x, y[0].y);
            fa1_0.u.y = pack_bf16_rne(y[1].x, y[1].y);
            fa1_0.u.z = pack_bf16_rne(y[2].x, y[2].y);
            fa1_0.u.w = pack_bf16_rne(y[3].x, y[3].y);
        }

        // tile0 MFMA (matrix pipe; tile1 VALU below overlaps its latency)
        v4f acc0_0 = {b2v0, b2v0, b2v0, b2v0};
        v4f acc1_0 = {b2v1, b2v1, b2v1, b2v1};
        acc0_0 = __builtin_amdgcn_mfma_f32_16x16x32_bf16(fa0_0.s, f00.s, acc0_0, 0, 0, 0);
        acc0_0 = __builtin_amdgcn_mfma_f32_16x16x32_bf16(fa1_0.s, f01.s, acc0_0, 0, 0, 0);
        acc1_0 = __builtin_amdgcn_mfma_f32_16x16x32_bf16(fa0_0.s, f10.s, acc1_0, 0, 0, 0);
        acc1_0 = __builtin_amdgcn_mfma_f32_16x16x32_bf16(fa1_0.s, f11.s, acc1_0, 0, 0, 0);

        // ---- tile1 fragments (independent chains: fills tile0 MFMA latency) ----
        FragU fa0_1, fa1_1;
        {
            Q2 P0, P1, Q0, Q1;
            P0.q = *(const float4*)(Ar1 + kA);
            P1.q = *(const float4*)(Ar1 + kA + 4);
            Q0.q = *(const float4*)(Br1 + kA);
            Q1.q = *(const float4*)(Br1 + kA + 4);
            f2 v[4] = {P0.h[0] + Q0.h[0], P0.h[1] + Q0.h[1],
                       P1.h[0] + Q1.h[0], P1.h[1] + Q1.h[1]};
            #pragma unroll
            for (int s = 0; s < 6; ++s) {
                const f2 scs = splat2(sc1[s]);
                #pragma unroll
                for (int c = 0; c < 4; ++c)
                    v[c] = pk_fma(scs, w1f[s][c], v[c]);
            }
            #pragma unroll
            for (int c = 0; c < 4; ++c) v[c] = gelu2(v[c]);
            fa0_1.u.x = pack_bf16_rne(v[0].x, v[0].y);
            fa0_1.u.y = pack_bf16_rne(v[1].x, v[1].y);
            fa0_1.u.z = pack_bf16_rne(v[2].x, v[2].y);
            fa0_1.u.w = pack_bf16_rne(v[3].x, v[3].y);
        }
        {
            Q2 P2, P3, Qv2, Q3;
            P2.q  = *(const float4*)(Ar1 + 32 + kA);
            P3.q  = *(const float4*)(Ar1 + 36 + kA);
            Qv2.q = *(const float4*)(Br1 + 32 + kA);
            Q3.q  = *(const float4*)(Br1 + 36 + kA);
            f2 y[4] = {P2.h[0] + Qv2.h[0], P2.h[1] + Qv2.h[1],
                       P3.h[0] + Q3.h[0],  P3.h[1] + Q3.h[1]};
            #pragma unroll
            for (int s = 0; s < 6; ++s) {
                const f2 scs = splat2(sc1[s]);
                #pragma unroll
                for (int c = 0; c < 4; ++c)
                    y[c] = pk_fma(scs, w1f[s][4 + c], y[c]);
            }
            #pragma unroll
            for (int c = 0; c < 4; ++c) y[c] = gelu2(y[c]);
            fa1_1.u.x = pack_bf16_rne(y[0].x, y[0].y);
            fa1_1.u.y = pack_bf16_rne(y[1].x, y[1].y);
            fa1_1.u.z = pack_bf16_rne(y[2].x, y[2].y);
            fa1_1.u.w = pack_bf16_rne(y[3].x, y[3].y);
        }

        v4f acc0_1 = {b2v0, b2v0, b2v0, b2v0};
        v4f acc1_1 = {b2v1, b2v1, b2v1, b2v1};
        acc0_1 = __builtin_amdgcn_mfma_f32_16x16x32_bf16(fa0_1.s, f00.s, acc0_1, 0, 0, 0);
        acc0_1 = __builtin_amdgcn_mfma_f32_16x16x32_bf16(fa1_1.s, f01.s, acc0_1, 0, 0, 0);
        acc1_1 = __builtin_amdgcn_mfma_f32_16x16x32_bf16(fa0_1.s, f10.s, acc1_1, 0, 0, 0);
        acc1_1 = __builtin_amdgcn_mfma_f32_16x16x32_bf16(fa1_1.s, f11.s, acc1_1, 0, 0, 0);

        // ---- epilogue tile0 (overlaps tile1 MFMA) ----
        {
            float cres[4];
            #pragma unroll
            for (int q = 0; q < 4; ++q) {
                const f2 g = gelu2(f2m(acc0_0[q], acc1_0[q]));
                cres[q] = row_reduce16(fmaf(g.y, w3v1, g.x * w3v0));
            }
            const int rsel = ml & 3;
            const float cs = (rsel & 2) ? ((rsel & 1) ? cres[3] : cres[2])
                                        : ((rsel & 1) ? cres[1] : cres[0]);
            const int pe = mtl0 * 16 + ql * 4 + rsel;
            const int swe = (pe >> 2) & 1;
            const float gate = sScal[pe * 8 + ((swe ^ 1) << 2) + 2];
            const float fe = sigmoid_(cs + b3s) * gate;
            if (ml < 4) {
                const int pi = sI[pe], pj = sJ[pe];
                sAdj[pi * 32 + pj] = fe;
                sAdj[pj * 32 + pi] = fe;
            }
        }
        // ---- epilogue tile1 (write guarded: tile 30 owned by (r=3,wv=2)) ----
        {
            float cres[4];
            #pragma unroll
            for (int q = 0; q < 4; ++q) {
                const f2 g = gelu2(f2m(acc0_1[q], acc1_1[q]));
                cres[q] = row_reduce16(fmaf(g.y, w3v1, g.x * w3v0));
            }
            const int rsel = ml & 3;
            const float cs = (rsel & 2) ? ((rsel & 1) ? cres[3] : cres[2])
                                        : ((rsel & 1) ? cres[1] : cres[0]);
            const int pe = mtl1c * 16 + ql * 4 + rsel;
            const int swe = (pe >> 2) & 1;
            const float gate = sScal[pe * 8 + ((swe ^ 1) << 2) + 2];
            const float fe = sigmoid_(cs + b3s) * gate;
            if (has1 && ml < 4) {
                const int pi = sI[pe], pj = sJ[pe];
                sAdj[pi * 32 + pj] = fe;
                sAdj[pj * 32 + pi] = fe;
            }
        }
    }
    __syncthreads();   // barrier 3

    // ---- coalesced tile writeback ----
    float* dst = out + (size_t)b * 1024;
    for (int idx = t; idx < 1024; idx += 256) dst[idx] = sAdj[idx];
}

extern "C" void kernel_launch(void* const* d_in, const int* in_sizes, int n_in,
                              void* d_out, int out_size, void* d_ws, size_t ws_size,
                              hipStream_t stream) {
    const float* cel   = (const float*)d_in[0];
    const float* theta = (const float*)d_in[1];
    const float* phi   = (const float*)d_in[2];
    const float* vel   = (const float*)d_in[3];
    const float* rad   = (const float*)d_in[4];
    const float* lon   = (const float*)d_in[5];
    const float* W1    = (const float*)d_in[6];
    const float* b1    = (const float*)d_in[7];
    const float* W2    = (const float*)d_in[8];
    const float* b2    = (const float*)d_in[9];
    const float* W3    = (const float*)d_in[10];
    const float* b3    = (const float*)d_in[11];
    const float* pw    = (const float*)d_in[12];
    float* out = (float*)d_out;

    const int B = in_sizes[1] / NN;  // theta is (B,N)
    edge_kernel<<<B, 256, 0, stream>>>(cel, theta, phi, vel, rad, lon,
                                       W1, b1, W2, b2, W3, b3, pw, out);
}

// Round 7
// 265.526 us; speedup vs baseline: 1.0056x; 1.0056x over previous
//
#include <hip/hip_runtime.h>
#include <hip/hip_bf16.h>
#include <math.h>

#define SS 8
#define NN 32
#define DD 64
#define NP 496   // 32*31/2
#define LDA 68   // padded row stride (floats) for sAi/sBj; 272B (16B-aligned)

typedef short v8s __attribute__((ext_vector_type(8)));   // 8 bf16 (4 VGPRs)
typedef float v4f __attribute__((ext_vector_type(4)));   // MFMA C/D frag
typedef float f2  __attribute__((ext_vector_type(2)));   // packed fp32 pair (VOP3P)

union FragU { uint4 u; v8s s; };
union Q2    { float4 q; f2 h[2]; };

static __device__ __forceinline__ f2 f2m(float a, float b) { f2 r; r.x = a; r.y = b; return r; }
static __device__ __forceinline__ f2 splat2(float s) { f2 r; r.x = s; r.y = s; return r; }
static __device__ __forceinline__ f2 pk_fma(f2 a, f2 b, f2 c) {
#if __has_builtin(__builtin_elementwise_fma)
    return __builtin_elementwise_fma(a, b, c);    // -> v_pk_fma_f32
#else
    return f2m(fmaf(a.x, b.x, c.x), fmaf(a.y, b.y, c.y));
#endif
}

__device__ __forceinline__ float wrap_pi(float d) {
    return fmaf(-6.28318530717958647692f, rintf(d * 0.15915494309189533577f), d);
}
// sigmoid via hw rcp (avoids the ~10-inst v_div refinement chain; 1e-7 rel err)
__device__ __forceinline__ float sigmoid_(float x) {
    return __builtin_amdgcn_rcpf(1.0f + __expf(-x));
}
// Sign-free packed GELU. erf via A&S 7.1.25-style rational (|eps|<=5e-4, no
// exp, 1 rcp/elem). gelu(x) = (0.5x + a) - (a*t^2)*t^2, a = 0.5|x|.
__device__ __forceinline__ f2 gelu2(f2 x) {
#if __has_builtin(__builtin_elementwise_max)
    f2 ax = __builtin_elementwise_max(x, -x);
#else
    f2 ax = f2m(fabsf(x.x), fabsf(x.y));
#endif
    f2 az = ax * splat2(0.70710678118654752440f);
    f2 d = pk_fma(splat2(0.078108f), az, splat2(0.000972f));
    d = pk_fma(d, az, splat2(0.230389f));
    d = pk_fma(d, az, splat2(0.278393f));
    d = pk_fma(d, az, splat2(1.0f));
    f2 t = f2m(__builtin_amdgcn_rcpf(d.x), __builtin_amdgcn_rcpf(d.y));
    f2 t2 = t * t;
    f2 a = ax * splat2(0.5f);
    f2 base = pk_fma(x, splat2(0.5f), a);
    f2 u = a * t2;
    return pk_fma(-u, t2, base);
}
// fp32 pair -> packed bf16 (RNE). HW path: v_cvt_pk_bf16_f32 on gfx950.
__device__ __forceinline__ unsigned int pack_bf16_rne(float x0, float x1) {
    union { __hip_bfloat162 h2; unsigned int u; } cv;
    float2 f; f.x = x0; f.y = x1;
    cv.h2 = __float22bfloat162_rn(f);
    return cv.u;
}
// Sum across each 16-lane DPP row via row_ror 8/4/2/1 (rotation butterfly:
// every lane ends with the full row sum, direction-agnostic). VALU pipe.
__device__ __forceinline__ float row_reduce16(float x) {
    int v;
    v = __builtin_amdgcn_update_dpp(0, __float_as_int(x), 0x128, 0xf, 0xf, false);
    x += __int_as_float(v);
    v = __builtin_amdgcn_update_dpp(0, __float_as_int(x), 0x124, 0xf, 0xf, false);
    x += __int_as_float(v);
    v = __builtin_amdgcn_update_dpp(0, __float_as_int(x), 0x122, 0xf, 0xf, false);
    x += __int_as_float(v);
    v = __builtin_amdgcn_update_dpp(0, __float_as_int(x), 0x121, 0xf, 0xf, false);
    x += __int_as_float(v);
    return x;
}
__device__ __forceinline__ uint4 build_w2_frag(const float* __restrict__ W2,
                                               int kb, int col) {
    uint4 pk;
    pk.x = pack_bf16_rne(W2[(kb + 0) * 32 + col], W2[(kb + 1) * 32 + col]);
    pk.y = pack_bf16_rne(W2[(kb + 2) * 32 + col], W2[(kb + 3) * 32 + col]);
    pk.z = pack_bf16_rne(W2[(kb + 4) * 32 + col], W2[(kb + 5) * 32 + col]);
    pk.w = pack_bf16_rne(W2[(kb + 6) * 32 + col], W2[(kb + 7) * 32 + col]);
    return pk;
}

// ---- load-only software pipeline macros (names static, no rotation movs) ----
// LOAD_IJ: packed (i | j<<8) pair index, fetched TWO rounds ahead.
#define LOAD_IJ(DST, MTL) DST = sIJ[(MTL) * 16 + ml];
// LOAD_RS: scalars + ks0 A/B rows, fetched ONE round ahead (addresses ready
// instantly from the prefetched ij -> no u8->addr->b128 serial chain in-round).
#define LOAD_RS(S0v, S1v, P0v, P1v, Q0v, Q1v, IJv, MTL)                    \
    {                                                                       \
        const int lp_ = (MTL) * 16 + ml;                                    \
        const int lsw_ = (lp_ >> 2) & 1;                                    \
        S0v.q = *(const float4*)&sScal[lp_ * 8 + (lsw_ << 2)];              \
        S1v.q = *(const float4*)&sScal[lp_ * 8 + ((lsw_ ^ 1) << 2)];        \
        const int li_ = (IJv) & 255, lj_ = (IJv) >> 8;                      \
        P0v.q = *(const float4*)&sAi[li_ * LDA + kA];                       \
        P1v.q = *(const float4*)&sAi[li_ * LDA + kA + 4];                   \
        Q0v.q = *(const float4*)&sBj[lj_ * LDA + kA];                       \
        Q1v.q = *(const float4*)&sBj[lj_ * LDA + kA + 4];                   \
    }
// COMPUTE_TILE: R3's round body, math-identical. ks1 rows load at top
// (addresses ready; latency hides under ks0 compute).
#define COMPUTE_TILE(S0v, S1v, P0v, P1v, Q0v, Q1v, IJv, MTL)               \
    {                                                                       \
        const int ci_ = (IJv) & 255, cj_ = (IJv) >> 8;                      \
        Q2 P2_, P3_, R2_, R3_;                                              \
        P2_.q = *(const float4*)&sAi[ci_ * LDA + 32 + kA];                  \
        P3_.q = *(const float4*)&sAi[ci_ * LDA + 36 + kA];                  \
        R2_.q = *(const float4*)&sBj[cj_ * LDA + 32 + kA];                  \
        R3_.q = *(const float4*)&sBj[cj_ * LDA + 36 + kA];                  \
        const float sc_[6] = {S0v.q.x, S0v.q.y, S0v.q.z, S0v.q.w,           \
                              S1v.q.x, S1v.q.y};                            \
        FragU fa0_, fa1_;                                                   \
        {                                                                   \
            f2 v_[4] = {P0v.h[0] + Q0v.h[0], P0v.h[1] + Q0v.h[1],           \
                        P1v.h[0] + Q1v.h[0], P1v.h[1] + Q1v.h[1]};          \
            _Pragma("unroll")                                               \
            for (int s_ = 0; s_ < 6; ++s_) {                                \
                const f2 scs_ = splat2(sc_[s_]);                            \
                _Pragma("unroll")                                           \
                for (int c_ = 0; c_ < 4; ++c_)                              \
                    v_[c_] = pk_fma(scs_, w1f[s_][c_], v_[c_]);             \
            }                                                               \
            _Pragma("unroll")                                               \
            for (int c_ = 0; c_ < 4; ++c_) v_[c_] = gelu2(v_[c_]);          \
            fa0_.u.x = pack_bf16_rne(v_[0].x, v_[0].y);                     \
            fa0_.u.y = pack_bf16_rne(v_[1].x, v_[1].y);                     \
            fa0_.u.z = pack_bf16_rne(v_[2].x, v_[2].y);                     \
            fa0_.u.w = pack_bf16_rne(v_[3].x, v_[3].y);                     \
        }                                                                   \
        {                                                                   \
            f2 y_[4] = {P2_.h[0] + R2_.h[0], P2_.h[1] + R2_.h[1],           \
                        P3_.h[0] + R3_.h[0], P3_.h[1] + R3_.h[1]};          \
            _Pragma("unroll")                                               \
            for (int s_ = 0; s_ < 6; ++s_) {                                \
                const f2 scs_ = splat2(sc_[s_]);                            \
                _Pragma("unroll")                                           \
                for (int c_ = 0; c_ < 4; ++c_)                              \
                    y_[c_] = pk_fma(scs_, w1f[s_][4 + c_], y_[c_]);         \
            }                                                               \
            _Pragma("unroll")                                               \
            for (int c_ = 0; c_ < 4; ++c_) y_[c_] = gelu2(y_[c_]);          \
            fa1_.u.x = pack_bf16_rne(y_[0].x, y_[0].y);                     \
            fa1_.u.y = pack_bf16_rne(y_[1].x, y_[1].y);                     \
            fa1_.u.z = pack_bf16_rne(y_[2].x, y_[2].y);                     \
            fa1_.u.w = pack_bf16_rne(y_[3].x, y_[3].y);                     \
        }                                                                   \
        v4f acc0_ = {b2v0, b2v0, b2v0, b2v0};                               \
        v4f acc1_ = {b2v1, b2v1, b2v1, b2v1};                               \
        acc0_ = __builtin_amdgcn_mfma_f32_16x16x32_bf16(fa0_.s, f00.s, acc0_, 0, 0, 0); \
        acc0_ = __builtin_amdgcn_mfma_f32_16x16x32_bf16(fa1_.s, f01.s, acc0_, 0, 0, 0); \
        acc1_ = __builtin_amdgcn_mfma_f32_16x16x32_bf16(fa0_.s, f10.s, acc1_, 0, 0, 0); \
        acc1_ = __builtin_amdgcn_mfma_f32_16x16x32_bf16(fa1_.s, f11.s, acc1_, 0, 0, 0); \
        float cres_[4];                                                     \
        _Pragma("unroll")                                                   \
        for (int q_ = 0; q_ < 4; ++q_) {                                    \
            const f2 g_ = gelu2(f2m(acc0_[q_], acc1_[q_]));                 \
            cres_[q_] = row_reduce16(fmaf(g_.y, w3v1, g_.x * w3v0));        \
        }                                                                   \
        const int rsel_ = ml & 3;                                           \
        const float cs_ = (rsel_ & 2) ? ((rsel_ & 1) ? cres_[3] : cres_[2]) \
                                      : ((rsel_ & 1) ? cres_[1] : cres_[0]);\
        const int pe_ = (MTL) * 16 + ql * 4 + rsel_;                        \
        const int swe_ = (pe_ >> 2) & 1;                                    \
        const float gate_ = sScal[pe_ * 8 + ((swe_ ^ 1) << 2) + 2];         \
        const float fe_ = sigmoid_(cs_ + b3s) * gate_;                      \
        if (ml < 4) {                                                       \
            const int ije_ = sIJ[pe_];                                      \
            const int pi_ = ije_ & 255, pj_ = ije_ >> 8;                    \
            sAdj[pi_ * 32 + pj_] = fe_;                                     \
            sAdj[pj_ * 32 + pi_] = fe_;                                     \
        }                                                                   \
    }

// History: R2 proved launch_bounds(256,4) caps VGPR at 64 -> scratch spill
// (FETCH 17->101MB, dur 89->138us). R4: block=512 diverges post-timing
// (abandoned). R5: hand-duplicated two-tile ILP -> VGPR 104, occ 20%,
// dur 101us (longer round critical path). R0-R3: static resources never move
// dur off 89.5us. This version: R3 structure + 3-stage LOAD-ONLY pipeline
// (ij 2 rounds ahead, rows+scal 1 round ahead) -> removes the per-round
// exposed LDS chain that unroll(disable) pins at the loop back-edge.
__global__ __launch_bounds__(256, 2) void edge_kernel(
    const float* __restrict__ cel,    // (B,S,N,D)
    const float* __restrict__ theta,  // (B,N)
    const float* __restrict__ phi,
    const float* __restrict__ vel,
    const float* __restrict__ rad,
    const float* __restrict__ lon,
    const float* __restrict__ W1,     // (134,64)
    const float* __restrict__ b1,     // (64)
    const float* __restrict__ W2,     // (64,32)
    const float* __restrict__ b2,     // (32)
    const float* __restrict__ W3,     // (32)
    const float* __restrict__ b3,     // (1)
    const float* __restrict__ pw,     // (6)
    float* __restrict__ out)          // (B,N,N)
{
    __shared__ __align__(16) float sAi[NN * LDA];     // fi@W1[0:64] + b1
    __shared__ __align__(16) float sBj[NN * LDA];     // fj@W1[64:128]
    __shared__ __align__(16) float sW1s[6 * 64];      // W1 rows 128..133
    __shared__ float sAdj[1024];
    __shared__ __align__(16) float sScal[NP * 8];     // f32, stride 8: {td,pd,vd,rr}|{ld,pr,gate,-}
    __shared__ unsigned short sIJ[NP];                // packed i | j<<8

    const int b = blockIdx.x;
    const int t = threadIdx.x;
    const int ml = t & 15;            // frag row-within-tile / C col
    const int ql = (t >> 4) & 3;      // frag k-quad / C row-quad (== lane>>4)
    const int wv = t >> 6;            // wave id 0..3
    const int kA = ql * 8;            // this lane's ks0 k-base

    // ---- B-fragments of W2 straight from global (per-thread, no LDS) ----
    FragU f00, f01, f10, f11;
    f00.u = build_w2_frag(W2, 0 * 32 + kA, 0 * 16 + ml);
    f01.u = build_w2_frag(W2, 1 * 32 + kA, 0 * 16 + ml);
    f10.u = build_w2_frag(W2, 0 * 32 + kA, 1 * 16 + ml);
    f11.u = build_w2_frag(W2, 1 * 32 + kA, 1 * 16 + ml);
    const float b2v0 = b2[ml], b2v1 = b2[16 + ml];
    const float w3v0 = W3[ml], w3v1 = W3[16 + ml];
    const float b3s  = b3[0];

    // ---- staging ----
    if (t < 31) {  // triu pair table (packed)
        int off = t * 31 - (t * (t - 1)) / 2;
        for (int j = t + 1; j < 32; ++j) {
            sIJ[off] = (unsigned short)(t | (j << 8));
            ++off;
        }
    }
    for (int idx = t; idx < 1024; idx += 256) sAdj[idx] = 0.0f;
    for (int idx = t; idx < 384; idx += 256) sW1s[idx] = W1[128 * 64 + idx];
    __syncthreads();   // barrier 1

    // ---- per-pair scalars + gate (node attrs straight from global: tiny,
    //      L1-broadcast). Gate packed into sScal chunk1 slot 2. ----
    for (int p = t; p < NP; p += 256) {
        const int ij = sIJ[p];
        const int i = ij & 255, j = ij >> 8;
        const float td = wrap_pi(theta[b * NN + i] - theta[b * NN + j]);
        const float pd = wrap_pi(phi[b * NN + i] - phi[b * NN + j]);
        const float vd = vel[b * NN + i] - vel[b * NN + j];
        const float rr = rad[b * NN + i] * __builtin_amdgcn_rcpf(rad[b * NN + j] + 1e-8f);
        const float ld = wrap_pi(lon[b * NN + i] - lon[b * NN + j]);
        const float pr = __cosf(td) * __cosf(pd);
        const float pf = fabsf(td) * pw[0] + fabsf(pd) * pw[1]
                       + fabsf(vd) * pw[2] + fabsf(rr - 1.0f) * pw[3]
                       + fabsf(ld) * pw[4] + fabsf(pr) * pw[5];
        const int sw = (p >> 2) & 1;   // chunk XOR-swizzle bit
        float4* c0 = (float4*)&sScal[p * 8 + (sw << 2)];
        float4* c1 = (float4*)&sScal[p * 8 + ((sw ^ 1) << 2)];
        *c0 = float4{td, pd, vd, rr};
        *c1 = float4{ld, pr, sigmoid_(pf), 0.0f};
    }

    // ---- phase A: node projections (packed fp32 VALU) ----
    {
        const int col = t & 63;
        const int w   = __builtin_amdgcn_readfirstlane(t >> 6);
        const float* fbase = cel + ((size_t)b * SS + (SS - 1)) * (NN * DD);
        f2 accA[8], accB[8];
        #pragma unroll
        for (int m = 0; m < 8; ++m) { accA[m] = splat2(0.0f); accB[m] = splat2(0.0f); }
        for (int k4 = 0; k4 < 64; k4 += 4) {
            const f2 wa01 = f2m(W1[(k4 + 0) * 64 + col], W1[(k4 + 1) * 64 + col]);
            const f2 wa23 = f2m(W1[(k4 + 2) * 64 + col], W1[(k4 + 3) * 64 + col]);
            const f2 wb01 = f2m(W1[(k4 + 64) * 64 + col], W1[(k4 + 65) * 64 + col]);
            const f2 wb23 = f2m(W1[(k4 + 66) * 64 + col], W1[(k4 + 67) * 64 + col]);
            #pragma unroll
            for (int m = 0; m < 8; ++m) {
                const float4 fv = *(const float4*)&fbase[(w + 4 * m) * 64 + k4]; // s_load_dwordx4
                accA[m] = pk_fma(f2m(fv.x, fv.y), wa01, accA[m]);
                accA[m] = pk_fma(f2m(fv.z, fv.w), wa23, accA[m]);
                accB[m] = pk_fma(f2m(fv.x, fv.y), wb01, accB[m]);
                accB[m] = pk_fma(f2m(fv.z, fv.w), wb23, accB[m]);
            }
        }
        const float b1c = b1[col];
        #pragma unroll
        for (int m = 0; m < 8; ++m) {
            sAi[(w + 4 * m) * LDA + col] = accA[m].x + accA[m].y + b1c;
            sBj[(w + 4 * m) * LDA + col] = accB[m].x + accB[m].y;
        }
    }
    __syncthreads();   // barrier 2

    // ---- hoist BOTH W1s halves for this lane (round-invariant). ----
    f2 w1f[6][8];
    #pragma unroll
    for (int s = 0; s < 6; ++s) {
        Q2 u0, u1, u2, u3;
        u0.q = *(const float4*)&sW1s[s * 64 + kA];
        u1.q = *(const float4*)&sW1s[s * 64 + kA + 4];
        u2.q = *(const float4*)&sW1s[s * 64 + 32 + kA];
        u3.q = *(const float4*)&sW1s[s * 64 + 36 + kA];
        w1f[s][0] = u0.h[0]; w1f[s][1] = u0.h[1];
        w1f[s][2] = u1.h[0]; w1f[s][3] = u1.h[1];
        w1f[s][4] = u2.h[0]; w1f[s][5] = u2.h[1];
        w1f[s][6] = u3.h[0]; w1f[s][7] = u3.h[1];
    }

    // ---- main loop: 8 rounds as 4x2 alternating bodies, load-only 3-stage
    //      pipeline (ij 2 ahead, rows+scal 1 ahead), ZERO barriers. Tile
    //      order per wave identical to R3: wv, wv+4, ..., wv+28 (skip 31). ----
    int ijA, ijB;
    Q2 SA0, SA1, PA0, PA1, QA0, QA1;
    Q2 SB0, SB1, PB0, PB1, QB0, QB1;
    LOAD_IJ(ijA, wv);                                    // round 0 indices
    LOAD_RS(SA0, SA1, PA0, PA1, QA0, QA1, ijA, wv);      // round 0 rows+scal
    LOAD_IJ(ijB, 4 + wv);                                // round 1 indices

    #pragma clang loop unroll(disable)
    for (int rr = 0; rr < 4; ++rr) {
        const int mtl0 = rr * 8 + wv;                    // even round, <=27: valid
        const int mtl1 = mtl0 + 4;                       // odd round, ==31 iff rr==3&&wv==3
        const bool v1 = (mtl1 < 31);                     // wave-uniform
        const int mtl1c = v1 ? mtl1 : 30;                // clamped (load-only)
        const int mtl2c = (mtl0 + 8 < 31) ? (mtl0 + 8) : 30;  // next even (clamped)
        const int mtl3c = (mtl1 + 8 < 31) ? (mtl1 + 8) : 30;  // next odd (clamped)

        // ---- body A: compute even round; prefetch odd rows + next-even ij ----
        LOAD_RS(SB0, SB1, PB0, PB1, QB0, QB1, ijB, mtl1c);
        const int ij0_ = ijA;
        LOAD_IJ(ijA, mtl2c);
        COMPUTE_TILE(SA0, SA1, PA0, PA1, QA0, QA1, ij0_, mtl0);

        // ---- body B: compute odd round; prefetch next-even rows + next-odd ij ----
        LOAD_RS(SA0, SA1, PA0, PA1, QA0, QA1, ijA, mtl2c);
        const int ij1_ = ijB;
        LOAD_IJ(ijB, mtl3c);
        if (v1) COMPUTE_TILE(SB0, SB1, PB0, PB1, QB0, QB1, ij1_, mtl1);
    }
    __syncthreads();   // barrier 3

    // ---- coalesced tile writeback ----
    float* dst = out + (size_t)b * 1024;
    for (int idx = t; idx < 1024; idx += 256) dst[idx] = sAdj[idx];
}

extern "C" void kernel_launch(void* const* d_in, const int* in_sizes, int n_in,
                              void* d_out, int out_size, void* d_ws, size_t ws_size,
                              hipStream_t stream) {
    const float* cel   = (const float*)d_in[0];
    const float* theta = (const float*)d_in[1];
    const float* phi   = (const float*)d_in[2];
    const float* vel   = (const float*)d_in[3];
    const float* rad   = (const float*)d_in[4];
    const float* lon   = (const float*)d_in[5];
    const float* W1    = (const float*)d_in[6];
    const float* b1    = (const float*)d_in[7];
    const float* W2    = (const float*)d_in[8];
    const float* b2    = (const float*)d_in[9];
    const float* W3    = (const float*)d_in[10];
    const float* b3    = (const float*)d_in[11];
    const float* pw    = (const float*)d_in[12];
    float* out = (float*)d_out;

    const int B = in_sizes[1] / NN;  // theta is (B,N)
    edge_kernel<<<B, 256, 0, stream>>>(cel, theta, phi, vel, rad, lon,
                                       W1, b1, W2, b2, W3, b3, pw, out);
}

// Round 8
// 256.414 us; speedup vs baseline: 1.0413x; 1.0355x over previous
//
#include <hip/hip_runtime.h>
#include <hip/hip_bf16.h>
#include <math.h>

#define SS 8
#define NN 32
#define DD 64
#define NP 496   // 32*31/2
#define LDA 68   // padded row stride (floats) for sAi/sBj; 272B (16B-aligned)

typedef short v8s __attribute__((ext_vector_type(8)));   // 8 bf16 (4 VGPRs)
typedef float v4f __attribute__((ext_vector_type(4)));   // MFMA C/D frag
typedef float f2  __attribute__((ext_vector_type(2)));   // packed fp32 pair (VOP3P)

union FragU { uint4 u; v8s s; };
union Q2    { float4 q; f2 h[2]; };

static __device__ __forceinline__ f2 f2m(float a, float b) { f2 r; r.x = a; r.y = b; return r; }
static __device__ __forceinline__ f2 splat2(float s) { f2 r; r.x = s; r.y = s; return r; }
static __device__ __forceinline__ f2 pk_fma(f2 a, f2 b, f2 c) {
#if __has_builtin(__builtin_elementwise_fma)
    return __builtin_elementwise_fma(a, b, c);    // -> v_pk_fma_f32
#else
    return f2m(fmaf(a.x, b.x, c.x), fmaf(a.y, b.y, c.y));
#endif
}

__device__ __forceinline__ float wrap_pi(float d) {
    return fmaf(-6.28318530717958647692f, rintf(d * 0.15915494309189533577f), d);
}
// sigmoid via hw rcp (avoids the ~10-inst v_div refinement chain; 1e-7 rel err)
__device__ __forceinline__ float sigmoid_(float x) {
    return __builtin_amdgcn_rcpf(1.0f + __expf(-x));
}
// Sign-free packed GELU. erf via A&S 7.1.25-style rational (|eps|<=5e-4, no
// exp, 1 rcp/elem). gelu(x) = (0.5x + a) - (a*t^2)*t^2, a = 0.5|x|.
__device__ __forceinline__ f2 gelu2(f2 x) {
#if __has_builtin(__builtin_elementwise_max)
    f2 ax = __builtin_elementwise_max(x, -x);
#else
    f2 ax = f2m(fabsf(x.x), fabsf(x.y));
#endif
    f2 az = ax * splat2(0.70710678118654752440f);
    f2 d = pk_fma(splat2(0.078108f), az, splat2(0.000972f));
    d = pk_fma(d, az, splat2(0.230389f));
    d = pk_fma(d, az, splat2(0.278393f));
    d = pk_fma(d, az, splat2(1.0f));
    f2 t = f2m(__builtin_amdgcn_rcpf(d.x), __builtin_amdgcn_rcpf(d.y));
    f2 t2 = t * t;
    f2 a = ax * splat2(0.5f);
    f2 base = pk_fma(x, splat2(0.5f), a);
    f2 u = a * t2;
    return pk_fma(-u, t2, base);
}
// fp32 pair -> packed bf16 (RNE). HW path: v_cvt_pk_bf16_f32 on gfx950.
__device__ __forceinline__ unsigned int pack_bf16_rne(float x0, float x1) {
    union { __hip_bfloat162 h2; unsigned int u; } cv;
    float2 f; f.x = x0; f.y = x1;
    cv.h2 = __float22bfloat162_rn(f);
    return cv.u;
}
// Sum across each 16-lane DPP row via row_ror 8/4/2/1 (rotation butterfly:
// every lane ends with the full row sum, direction-agnostic). VALU pipe.
__device__ __forceinline__ float row_reduce16(float x) {
    int v;
    v = __builtin_amdgcn_update_dpp(0, __float_as_int(x), 0x128, 0xf, 0xf, false);
    x += __int_as_float(v);
    v = __builtin_amdgcn_update_dpp(0, __float_as_int(x), 0x124, 0xf, 0xf, false);
    x += __int_as_float(v);
    v = __builtin_amdgcn_update_dpp(0, __float_as_int(x), 0x122, 0xf, 0xf, false);
    x += __int_as_float(v);
    v = __builtin_amdgcn_update_dpp(0, __float_as_int(x), 0x121, 0xf, 0xf, false);
    x += __int_as_float(v);
    return x;
}
__device__ __forceinline__ uint4 build_w2_frag(const float* __restrict__ W2,
                                               int kb, int col) {
    uint4 pk;
    pk.x = pack_bf16_rne(W2[(kb + 0) * 32 + col], W2[(kb + 1) * 32 + col]);
    pk.y = pack_bf16_rne(W2[(kb + 2) * 32 + col], W2[(kb + 3) * 32 + col]);
    pk.z = pack_bf16_rne(W2[(kb + 4) * 32 + col], W2[(kb + 5) * 32 + col]);
    pk.w = pack_bf16_rne(W2[(kb + 6) * 32 + col], W2[(kb + 7) * 32 + col]);
    return pk;
}

// History: R2: launch_bounds(256,4) caps VGPR at 64 -> scratch spill (FETCH
// 17->101MB, dur 89->138us). R4: block=512 diverges post-timing (abandoned).
// R5/R7: ILP pipelining (+20 VGPR) -> occ 28->20%, dur 98-101us. Measured
// occupancy tracks VGPR-permitted waves/SIMD (64:38.5%, 84:28%, 104:20%).
// R0 vs R3: LDS 41984->39936 changed NOTHING -- consistent with a 2KB LDS
// allocation granularity (39936 rounds to 40960 -> still 3 blocks/CU).
// This version: drop sW1s (w1f hoist reads global W1 directly; 34KB,
// L1-broadcast, once per kernel) -> LDS 38368, 4 blocks/CU under ANY
// granularity <=2KB. Math bit-identical to R3 (89.5us best).
__global__ __launch_bounds__(256, 2) void edge_kernel(
    const float* __restrict__ cel,    // (B,S,N,D)
    const float* __restrict__ theta,  // (B,N)
    const float* __restrict__ phi,
    const float* __restrict__ vel,
    const float* __restrict__ rad,
    const float* __restrict__ lon,
    const float* __restrict__ W1,     // (134,64)
    const float* __restrict__ b1,     // (64)
    const float* __restrict__ W2,     // (64,32)
    const float* __restrict__ b2,     // (32)
    const float* __restrict__ W3,     // (32)
    const float* __restrict__ b3,     // (1)
    const float* __restrict__ pw,     // (6)
    float* __restrict__ out)          // (B,N,N)
{
    __shared__ __align__(16) float sAi[NN * LDA];     // fi@W1[0:64] + b1
    __shared__ __align__(16) float sBj[NN * LDA];     // fj@W1[64:128]
    __shared__ float sAdj[1024];
    __shared__ __align__(16) float sScal[NP * 8];     // f32, stride 8: {td,pd,vd,rr}|{ld,pr,gate,-}
    __shared__ unsigned char sI[NP], sJ[NP];

    const int b = blockIdx.x;
    const int t = threadIdx.x;
    const int ml = t & 15;            // frag row-within-tile / C col
    const int ql = (t >> 4) & 3;      // frag k-quad / C row-quad (== lane>>4)
    const int wv = t >> 6;            // wave id
    const int kA = ql * 8;            // this lane's ks0 k-base

    // ---- B-fragments of W2 straight from global (per-thread, no LDS) ----
    FragU f00, f01, f10, f11;
    f00.u = build_w2_frag(W2, 0 * 32 + kA, 0 * 16 + ml);
    f01.u = build_w2_frag(W2, 1 * 32 + kA, 0 * 16 + ml);
    f10.u = build_w2_frag(W2, 0 * 32 + kA, 1 * 16 + ml);
    f11.u = build_w2_frag(W2, 1 * 32 + kA, 1 * 16 + ml);
    const float b2v0 = b2[ml], b2v1 = b2[16 + ml];
    const float w3v0 = W3[ml], w3v1 = W3[16 + ml];
    const float b3s  = b3[0];

    // ---- staging ----
    if (t < 31) {  // triu pair table
        int off = t * 31 - (t * (t - 1)) / 2;
        for (int j = t + 1; j < 32; ++j) {
            sI[off] = (unsigned char)t;
            sJ[off] = (unsigned char)j;
            ++off;
        }
    }
    for (int idx = t; idx < 1024; idx += 256) sAdj[idx] = 0.0f;
    __syncthreads();   // barrier 1

    // ---- per-pair scalars + gate (node attrs straight from global: tiny,
    //      L1-broadcast). Gate packed into sScal chunk1 slot 2. ----
    for (int p = t; p < NP; p += 256) {
        const int i = sI[p], j = sJ[p];
        const float td = wrap_pi(theta[b * NN + i] - theta[b * NN + j]);
        const float pd = wrap_pi(phi[b * NN + i] - phi[b * NN + j]);
        const float vd = vel[b * NN + i] - vel[b * NN + j];
        const float rr = rad[b * NN + i] * __builtin_amdgcn_rcpf(rad[b * NN + j] + 1e-8f);
        const float ld = wrap_pi(lon[b * NN + i] - lon[b * NN + j]);
        const float pr = __cosf(td) * __cosf(pd);
        const float pf = fabsf(td) * pw[0] + fabsf(pd) * pw[1]
                       + fabsf(vd) * pw[2] + fabsf(rr - 1.0f) * pw[3]
                       + fabsf(ld) * pw[4] + fabsf(pr) * pw[5];
        const int sw = (p >> 2) & 1;   // chunk XOR-swizzle bit
        float4* c0 = (float4*)&sScal[p * 8 + (sw << 2)];
        float4* c1 = (float4*)&sScal[p * 8 + ((sw ^ 1) << 2)];
        *c0 = float4{td, pd, vd, rr};
        *c1 = float4{ld, pr, sigmoid_(pf), 0.0f};
    }

    // ---- phase A: node projections (packed fp32 VALU) ----
    {
        const int col = t & 63;
        const int w   = __builtin_amdgcn_readfirstlane(t >> 6);
        const float* fbase = cel + ((size_t)b * SS + (SS - 1)) * (NN * DD);
        f2 accA[8], accB[8];
        #pragma unroll
        for (int m = 0; m < 8; ++m) { accA[m] = splat2(0.0f); accB[m] = splat2(0.0f); }
        for (int k4 = 0; k4 < 64; k4 += 4) {
            const f2 wa01 = f2m(W1[(k4 + 0) * 64 + col], W1[(k4 + 1) * 64 + col]);
            const f2 wa23 = f2m(W1[(k4 + 2) * 64 + col], W1[(k4 + 3) * 64 + col]);
            const f2 wb01 = f2m(W1[(k4 + 64) * 64 + col], W1[(k4 + 65) * 64 + col]);
            const f2 wb23 = f2m(W1[(k4 + 66) * 64 + col], W1[(k4 + 67) * 64 + col]);
            #pragma unroll
            for (int m = 0; m < 8; ++m) {
                const float4 fv = *(const float4*)&fbase[(w + 4 * m) * 64 + k4]; // s_load_dwordx4
                accA[m] = pk_fma(f2m(fv.x, fv.y), wa01, accA[m]);
                accA[m] = pk_fma(f2m(fv.z, fv.w), wa23, accA[m]);
                accB[m] = pk_fma(f2m(fv.x, fv.y), wb01, accB[m]);
                accB[m] = pk_fma(f2m(fv.z, fv.w), wb23, accB[m]);
            }
        }
        const float b1c = b1[col];
        #pragma unroll
        for (int m = 0; m < 8; ++m) {
            sAi[(w + 4 * m) * LDA + col] = accA[m].x + accA[m].y + b1c;
            sBj[(w + 4 * m) * LDA + col] = accB[m].x + accB[m].y;
        }
    }
    __syncthreads();   // barrier 2

    // ---- hoist BOTH W1s halves for this lane (round-invariant), straight
    // from GLOBAL W1 rows 128..133 (34KB table, L1-broadcast across the
    // 16-lane groups; read once per kernel -> no LDS staging needed). ----
    const float* W1s = W1 + 128 * 64;
    f2 w1f[6][8];
    #pragma unroll
    for (int s = 0; s < 6; ++s) {
        Q2 u0, u1, u2, u3;
        u0.q = *(const float4*)&W1s[s * 64 + kA];
        u1.q = *(const float4*)&W1s[s * 64 + kA + 4];
        u2.q = *(const float4*)&W1s[s * 64 + 32 + kA];
        u3.q = *(const float4*)&W1s[s * 64 + 36 + kA];
        w1f[s][0] = u0.h[0]; w1f[s][1] = u0.h[1];
        w1f[s][2] = u1.h[0]; w1f[s][3] = u1.h[1];
        w1f[s][4] = u2.h[0]; w1f[s][5] = u2.h[1];
        w1f[s][6] = u3.h[0]; w1f[s][7] = u3.h[1];
    }

    // ---- main loop: one 16-pair m-tile per wave-round, ZERO barriers ----
    #pragma clang loop unroll(disable)
    for (int r = 0; r < 8; ++r) {
        const int mtl = r * 4 + wv;
        if (mtl >= 31) break;                    // wave-uniform
        const int p = mtl * 16 + ml;
        const int i = sI[p], j = sJ[p];
        const int sw = (p >> 2) & 1;
        Q2 S0, S1;
        S0.q = *(const float4*)&sScal[p * 8 + (sw << 2)];        // td,pd,vd,rr
        S1.q = *(const float4*)&sScal[p * 8 + ((sw ^ 1) << 2)];  // ld,pr,gate,-
        const float sc[6] = {S0.q.x, S0.q.y, S0.q.z, S0.q.w, S1.q.x, S1.q.y};
        const float* Ar = &sAi[i * LDA];
        const float* Br = &sBj[j * LDA];

        // ks0 half: k = kA..kA+7 (W1s from registers)
        FragU fa0, fa1;
        {
            Q2 P0, P1, Q0, Q1;
            P0.q = *(const float4*)(Ar + kA);
            P1.q = *(const float4*)(Ar + kA + 4);
            Q0.q = *(const float4*)(Br + kA);
            Q1.q = *(const float4*)(Br + kA + 4);
            f2 v[4] = {P0.h[0] + Q0.h[0], P0.h[1] + Q0.h[1],
                       P1.h[0] + Q1.h[0], P1.h[1] + Q1.h[1]};
            #pragma unroll
            for (int s = 0; s < 6; ++s) {
                const f2 scs = splat2(sc[s]);
                #pragma unroll
                for (int c = 0; c < 4; ++c)
                    v[c] = pk_fma(scs, w1f[s][c], v[c]);
            }
            #pragma unroll
            for (int c = 0; c < 4; ++c) v[c] = gelu2(v[c]);
            fa0.u.x = pack_bf16_rne(v[0].x, v[0].y);
            fa0.u.y = pack_bf16_rne(v[1].x, v[1].y);
            fa0.u.z = pack_bf16_rne(v[2].x, v[2].y);
            fa0.u.w = pack_bf16_rne(v[3].x, v[3].y);
        }
        // ks1 half: k = 32+kA.. (W1s from registers)
        {
            Q2 P2, P3, Q2v, Q3;
            P2.q  = *(const float4*)(Ar + 32 + kA);
            P3.q  = *(const float4*)(Ar + 36 + kA);
            Q2v.q = *(const float4*)(Br + 32 + kA);
            Q3.q  = *(const float4*)(Br + 36 + kA);
            f2 y[4] = {P2.h[0] + Q2v.h[0], P2.h[1] + Q2v.h[1],
                       P3.h[0] + Q3.h[0],  P3.h[1] + Q3.h[1]};
            #pragma unroll
            for (int s = 0; s < 6; ++s) {
                const f2 scs = splat2(sc[s]);
                #pragma unroll
                for (int c = 0; c < 4; ++c)
                    y[c] = pk_fma(scs, w1f[s][4 + c], y[c]);
            }
            #pragma unroll
            for (int c = 0; c < 4; ++c) y[c] = gelu2(y[c]);
            fa1.u.x = pack_bf16_rne(y[0].x, y[0].y);
            fa1.u.y = pack_bf16_rne(y[1].x, y[1].y);
            fa1.u.z = pack_bf16_rne(y[2].x, y[2].y);
            fa1.u.w = pack_bf16_rne(y[3].x, y[3].y);
        }

        // h2 = h1 @ W2 on the matrix pipe
        v4f acc0 = {b2v0, b2v0, b2v0, b2v0};
        v4f acc1 = {b2v1, b2v1, b2v1, b2v1};
        acc0 = __builtin_amdgcn_mfma_f32_16x16x32_bf16(fa0.s, f00.s, acc0, 0, 0, 0);
        acc0 = __builtin_amdgcn_mfma_f32_16x16x32_bf16(fa1.s, f01.s, acc0, 0, 0, 0);
        acc1 = __builtin_amdgcn_mfma_f32_16x16x32_bf16(fa0.s, f10.s, acc1, 0, 0, 0);
        acc1 = __builtin_amdgcn_mfma_f32_16x16x32_bf16(fa1.s, f11.s, acc1, 0, 0, 0);

        // epilogue: pk gelu + W3 dot (row_ror reduce leaves sum in EVERY lane)
        // -> lane rsel=ml&3 picks its pair -> ONE sigmoid/gate per tile.
        float cres[4];
        #pragma unroll
        for (int rr = 0; rr < 4; ++rr) {
            const f2 g = gelu2(f2m(acc0[rr], acc1[rr]));
            cres[rr] = row_reduce16(fmaf(g.y, w3v1, g.x * w3v0));
        }
        const int rsel = ml & 3;     // constant-index ternary: no scratch
        const float cs = (rsel & 2) ? ((rsel & 1) ? cres[3] : cres[2])
                                    : ((rsel & 1) ? cres[1] : cres[0]);
        const int pe = mtl * 16 + ql * 4 + rsel;
        const int swe = (pe >> 2) & 1;
        const float gate = sScal[pe * 8 + ((swe ^ 1) << 2) + 2];
        const float fe = sigmoid_(cs + b3s) * gate;
        if (ml < 4) {
            const int pi = sI[pe], pj = sJ[pe];
            sAdj[pi * 32 + pj] = fe;
            sAdj[pj * 32 + pi] = fe;
        }
    }
    __syncthreads();   // barrier 3

    // ---- coalesced tile writeback ----
    float* dst = out + (size_t)b * 1024;
    for (int idx = t; idx < 1024; idx += 256) dst[idx] = sAdj[idx];
}

extern "C" void kernel_launch(void* const* d_in, const int* in_sizes, int n_in,
                              void* d_out, int out_size, void* d_ws, size_t ws_size,
                              hipStream_t stream) {
    const float* cel   = (const float*)d_in[0];
    const float* theta = (const float*)d_in[1];
    const float* phi   = (const float*)d_in[2];
    const float* vel   = (const float*)d_in[3];
    const float* rad   = (const float*)d_in[4];
    const float* lon   = (const float*)d_in[5];
    const float* W1    = (const float*)d_in[6];
    const float* b1    = (const float*)d_in[7];
    const float* W2    = (const float*)d_in[8];
    const float* b2    = (const float*)d_in[9];
    const float* W3    = (const float*)d_in[10];
    const float* b3    = (const float*)d_in[11];
    const float* pw    = (const float*)d_in[12];
    float* out = (float*)d_out;

    const int B = in_sizes[1] / NN;  // theta is (B,N)
    edge_kernel<<<B, 256, 0, stream>>>(cel, theta, phi, vel, rad, lon,
                                       W1, b1, W2, b2, W3, b3, pw, out);
}

// Round 9
// 238.782 us; speedup vs baseline: 1.1182x; 1.0738x over previous
//
#include <hip/hip_runtime.h>
#include <hip/hip_bf16.h>
#include <math.h>

#define SS 8
#define NN 32
#define DD 64
#define NP 496   // 32*31/2
#define LDA 68   // padded row stride (floats) for sAi/sBj; 272B (16B-aligned)

typedef short v8s __attribute__((ext_vector_type(8)));   // 8 bf16 (4 VGPRs)
typedef float v4f __attribute__((ext_vector_type(4)));   // MFMA C/D frag
typedef float f2  __attribute__((ext_vector_type(2)));   // packed fp32 pair (VOP3P)

union FragU { uint4 u; v8s s; };
union Q2    { float4 q; f2 h[2]; };

static __device__ __forceinline__ f2 f2m(float a, float b) { f2 r; r.x = a; r.y = b; return r; }
static __device__ __forceinline__ f2 splat2(float s) { f2 r; r.x = s; r.y = s; return r; }
static __device__ __forceinline__ f2 pk_fma(f2 a, f2 b, f2 c) {
#if __has_builtin(__builtin_elementwise_fma)
    return __builtin_elementwise_fma(a, b, c);    // -> v_pk_fma_f32
#else
    return f2m(fmaf(a.x, b.x, c.x), fmaf(a.y, b.y, c.y));
#endif
}

__device__ __forceinline__ float wrap_pi(float d) {
    return fmaf(-6.28318530717958647692f, rintf(d * 0.15915494309189533577f), d);
}
// sigmoid via hw rcp (avoids the ~10-inst v_div refinement chain; 1e-7 rel err)
__device__ __forceinline__ float sigmoid_(float x) {
    return __builtin_amdgcn_rcpf(1.0f + __expf(-x));
}
// Sign-free packed GELU. erf via A&S 7.1.27-style quartic (|eps|<=5e-4, no
// exp, 1 rcp/elem). gelu(x) = (0.5x + a) - (a*t^2)*t^2, a = 0.5|x|.
__device__ __forceinline__ f2 gelu2(f2 x) {
#if __has_builtin(__builtin_elementwise_max)
    f2 ax = __builtin_elementwise_max(x, -x);
#else
    f2 ax = f2m(fabsf(x.x), fabsf(x.y));
#endif
    f2 az = ax * splat2(0.70710678118654752440f);
    f2 d = pk_fma(splat2(0.078108f), az, splat2(0.000972f));
    d = pk_fma(d, az, splat2(0.230389f));
    d = pk_fma(d, az, splat2(0.278393f));
    d = pk_fma(d, az, splat2(1.0f));
    f2 t = f2m(__builtin_amdgcn_rcpf(d.x), __builtin_amdgcn_rcpf(d.y));
    f2 t2 = t * t;
    f2 a = ax * splat2(0.5f);
    f2 base = pk_fma(x, splat2(0.5f), a);
    f2 u = a * t2;
    return pk_fma(-u, t2, base);
}
// fp32 pair -> packed bf16 (RNE). HW path: v_cvt_pk_bf16_f32 on gfx950.
__device__ __forceinline__ unsigned int pack_bf16_rne(float x0, float x1) {
    union { __hip_bfloat162 h2; unsigned int u; } cv;
    float2 f; f.x = x0; f.y = x1;
    cv.h2 = __float22bfloat162_rn(f);
    return cv.u;
}
// residual-lo pack: bf16(x - f32(bf16_hi(x))) for a packed hi word.
// low 16 bits of hw = bf16(x0), high 16 = bf16(x1).
__device__ __forceinline__ unsigned int res_pack(unsigned int hw, float x0, float x1) {
    const float f0 = __uint_as_float(hw << 16);
    const float f1 = __uint_as_float(hw & 0xFFFF0000u);
    return pack_bf16_rne(x0 - f0, x1 - f1);
}
// Sum across each 16-lane DPP row via row_ror 8/4/2/1 (rotation butterfly:
// every lane ends with the full row sum, direction-agnostic). VALU pipe.
__device__ __forceinline__ float row_reduce16(float x) {
    int v;
    v = __builtin_amdgcn_update_dpp(0, __float_as_int(x), 0x128, 0xf, 0xf, false);
    x += __int_as_float(v);
    v = __builtin_amdgcn_update_dpp(0, __float_as_int(x), 0x124, 0xf, 0xf, false);
    x += __int_as_float(v);
    v = __builtin_amdgcn_update_dpp(0, __float_as_int(x), 0x122, 0xf, 0xf, false);
    x += __int_as_float(v);
    v = __builtin_amdgcn_update_dpp(0, __float_as_int(x), 0x121, 0xf, 0xf, false);
    x += __int_as_float(v);
    return x;
}
__device__ __forceinline__ uint4 build_w2_frag(const float* __restrict__ W2,
                                               int kb, int col) {
    uint4 pk;
    pk.x = pack_bf16_rne(W2[(kb + 0) * 32 + col], W2[(kb + 1) * 32 + col]);
    pk.y = pack_bf16_rne(W2[(kb + 2) * 32 + col], W2[(kb + 3) * 32 + col]);
    pk.z = pack_bf16_rne(W2[(kb + 4) * 32 + col], W2[(kb + 5) * 32 + col]);
    pk.w = pack_bf16_rne(W2[(kb + 6) * 32 + col], W2[(kb + 7) * 32 + col]);
    return pk;
}

// History: R2: launch_bounds(256,4) caps VGPR at 64 -> scratch spill. R4:
// block=512 diverges post-timing (abandoned). R5/R7: +20 VGPR ILP pipelines
// -> occ 28->20%, dur 98-101us. R0/R3/R8: LDS 42->39.9->38.4KB all dur
// ~89.5us, occ ~28% -- static resources exhausted as an axis. VALUBusy ~57%
// with MfmaUtil 1.9% -> the only lever left is fewer VALU issues. This
// version: phase A (2x 32x64x64 matmul, ~650 VALU issues/thread as pk_fma)
// moves to the idle MATRIX pipe: split-bf16 A (hi + residual-lo, 2-product)
// x bf16 W1, b1 folded into MFMA C-init. Error ~1e-3 < existing h1-bf16
// quantization; threshold 0.0118, current absmax 0.0039. nt-loop serial to
// cap VGPR liveness (R5/R7 lesson). Everything else byte-identical to R8.
__global__ __launch_bounds__(256, 2) void edge_kernel(
    const float* __restrict__ cel,    // (B,S,N,D)
    const float* __restrict__ theta,  // (B,N)
    const float* __restrict__ phi,
    const float* __restrict__ vel,
    const float* __restrict__ rad,
    const float* __restrict__ lon,
    const float* __restrict__ W1,     // (134,64)
    const float* __restrict__ b1,     // (64)
    const float* __restrict__ W2,     // (64,32)
    const float* __restrict__ b2,     // (32)
    const float* __restrict__ W3,     // (32)
    const float* __restrict__ b3,     // (1)
    const float* __restrict__ pw,     // (6)
    float* __restrict__ out)          // (B,N,N)
{
    __shared__ __align__(16) float sAi[NN * LDA];     // fi@W1[0:64] + b1
    __shared__ __align__(16) float sBj[NN * LDA];     // fj@W1[64:128]
    __shared__ float sAdj[1024];
    __shared__ __align__(16) float sScal[NP * 8];     // f32, stride 8: {td,pd,vd,rr}|{ld,pr,gate,-}
    __shared__ unsigned char sI[NP], sJ[NP];

    const int b = blockIdx.x;
    const int t = threadIdx.x;
    const int ml = t & 15;            // frag row-within-tile / C col
    const int ql = (t >> 4) & 3;      // frag k-quad / C row-quad (== lane>>4)
    const int wv = t >> 6;            // wave id
    const int kA = ql * 8;            // this lane's ks0 k-base

    // ---- B-fragments of W2 straight from global (per-thread, no LDS) ----
    FragU f00, f01, f10, f11;
    f00.u = build_w2_frag(W2, 0 * 32 + kA, 0 * 16 + ml);
    f01.u = build_w2_frag(W2, 1 * 32 + kA, 0 * 16 + ml);
    f10.u = build_w2_frag(W2, 0 * 32 + kA, 1 * 16 + ml);
    f11.u = build_w2_frag(W2, 1 * 32 + kA, 1 * 16 + ml);
    const float b2v0 = b2[ml], b2v1 = b2[16 + ml];
    const float w3v0 = W3[ml], w3v1 = W3[16 + ml];
    const float b3s  = b3[0];

    // ---- staging ----
    if (t < 31) {  // triu pair table
        int off = t * 31 - (t * (t - 1)) / 2;
        for (int j = t + 1; j < 32; ++j) {
            sI[off] = (unsigned char)t;
            sJ[off] = (unsigned char)j;
            ++off;
        }
    }
    for (int idx = t; idx < 1024; idx += 256) sAdj[idx] = 0.0f;
    __syncthreads();   // barrier 1

    // ---- per-pair scalars + gate (node attrs straight from global: tiny,
    //      L1-broadcast). Gate packed into sScal chunk1 slot 2. ----
    for (int p = t; p < NP; p += 256) {
        const int i = sI[p], j = sJ[p];
        const float td = wrap_pi(theta[b * NN + i] - theta[b * NN + j]);
        const float pd = wrap_pi(phi[b * NN + i] - phi[b * NN + j]);
        const float vd = vel[b * NN + i] - vel[b * NN + j];
        const float rr = rad[b * NN + i] * __builtin_amdgcn_rcpf(rad[b * NN + j] + 1e-8f);
        const float ld = wrap_pi(lon[b * NN + i] - lon[b * NN + j]);
        const float pr = __cosf(td) * __cosf(pd);
        const float pf = fabsf(td) * pw[0] + fabsf(pd) * pw[1]
                       + fabsf(vd) * pw[2] + fabsf(rr - 1.0f) * pw[3]
                       + fabsf(ld) * pw[4] + fabsf(pr) * pw[5];
        const int sw = (p >> 2) & 1;   // chunk XOR-swizzle bit
        float4* c0 = (float4*)&sScal[p * 8 + (sw << 2)];
        float4* c1 = (float4*)&sScal[p * 8 + ((sw ^ 1) << 2)];
        *c0 = float4{td, pd, vd, rr};
        *c1 = float4{ld, pr, sigmoid_(pf), 0.0f};
    }

    // ---- phase A on the MATRIX pipe: {Ai,Bj}(32x64) = F(32x64)@W1half(64x64).
    // Wave w4: target tg=w4>>1 (0=Ai rows0..63 of W1, 1=Bj rows64..127),
    // M-tile mt=w4&1 (node rows mt*16..+15). A = feats as bf16 hi + residual
    // lo (2-product split); B = W1 bf16 (err class == existing h1-bf16 cast).
    // b1 folded into C-init for tg=0. Same lane layout as the proven h1@W2
    // MFMA: A[row=ml][k=kA+e], B[k][col=ml], C col=ml row=ql*4+reg. ----
    {
        const int w4 = __builtin_amdgcn_readfirstlane(t >> 6);
        const int tg = w4 >> 1;
        const int mt = w4 & 1;
        const float* fbase = cel + ((size_t)b * SS + (SS - 1)) * (NN * DD);
        const float* Arow = fbase + (mt * 16 + ml) * 64;
        const float4 e0 = *(const float4*)(Arow + kA);
        const float4 e1 = *(const float4*)(Arow + kA + 4);
        const float4 e2 = *(const float4*)(Arow + 32 + kA);
        const float4 e3 = *(const float4*)(Arow + 36 + kA);
        FragU Ah0, Al0, Ah1, Al1;
        Ah0.u.x = pack_bf16_rne(e0.x, e0.y);
        Ah0.u.y = pack_bf16_rne(e0.z, e0.w);
        Ah0.u.z = pack_bf16_rne(e1.x, e1.y);
        Ah0.u.w = pack_bf16_rne(e1.z, e1.w);
        Al0.u.x = res_pack(Ah0.u.x, e0.x, e0.y);
        Al0.u.y = res_pack(Ah0.u.y, e0.z, e0.w);
        Al0.u.z = res_pack(Ah0.u.z, e1.x, e1.y);
        Al0.u.w = res_pack(Ah0.u.w, e1.z, e1.w);
        Ah1.u.x = pack_bf16_rne(e2.x, e2.y);
        Ah1.u.y = pack_bf16_rne(e2.z, e2.w);
        Ah1.u.z = pack_bf16_rne(e3.x, e3.y);
        Ah1.u.w = pack_bf16_rne(e3.z, e3.w);
        Al1.u.x = res_pack(Ah1.u.x, e2.x, e2.y);
        Al1.u.y = res_pack(Ah1.u.y, e2.z, e2.w);
        Al1.u.z = res_pack(Ah1.u.z, e3.x, e3.y);
        Al1.u.w = res_pack(Ah1.u.w, e3.z, e3.w);

        const float* WB = W1 + (tg * 64) * 64;
        float* dstS = tg ? sBj : sAi;
        #pragma clang loop unroll(disable)   // serial nt: cap VGPR liveness
        for (int nt = 0; nt < 4; ++nt) {
            const int colb = nt * 16 + ml;
            const float* B0p = WB + kA * 64 + colb;          // k = kA+e
            const float* B1p = WB + (32 + kA) * 64 + colb;   // k = 32+kA+e
            FragU B0, B1;
            B0.u.x = pack_bf16_rne(B0p[0],   B0p[64]);
            B0.u.y = pack_bf16_rne(B0p[128], B0p[192]);
            B0.u.z = pack_bf16_rne(B0p[256], B0p[320]);
            B0.u.w = pack_bf16_rne(B0p[384], B0p[448]);
            B1.u.x = pack_bf16_rne(B1p[0],   B1p[64]);
            B1.u.y = pack_bf16_rne(B1p[128], B1p[192]);
            B1.u.z = pack_bf16_rne(B1p[256], B1p[320]);
            B1.u.w = pack_bf16_rne(B1p[384], B1p[448]);
            const float cinit = tg ? 0.0f : b1[colb];
            v4f acc = {cinit, cinit, cinit, cinit};
            acc = __builtin_amdgcn_mfma_f32_16x16x32_bf16(Ah0.s, B0.s, acc, 0, 0, 0);
            acc = __builtin_amdgcn_mfma_f32_16x16x32_bf16(Al0.s, B0.s, acc, 0, 0, 0);
            acc = __builtin_amdgcn_mfma_f32_16x16x32_bf16(Ah1.s, B1.s, acc, 0, 0, 0);
            acc = __builtin_amdgcn_mfma_f32_16x16x32_bf16(Al1.s, B1.s, acc, 0, 0, 0);
            dstS[(mt * 16 + ql * 4 + 0) * LDA + colb] = acc[0];
            dstS[(mt * 16 + ql * 4 + 1) * LDA + colb] = acc[1];
            dstS[(mt * 16 + ql * 4 + 2) * LDA + colb] = acc[2];
            dstS[(mt * 16 + ql * 4 + 3) * LDA + colb] = acc[3];
        }
    }
    __syncthreads();   // barrier 2

    // ---- hoist BOTH W1s halves for this lane (round-invariant), straight
    // from GLOBAL W1 rows 128..133 (34KB table, L1-broadcast across the
    // 16-lane groups; read once per kernel -> no LDS staging needed). ----
    const float* W1s = W1 + 128 * 64;
    f2 w1f[6][8];
    #pragma unroll
    for (int s = 0; s < 6; ++s) {
        Q2 u0, u1, u2, u3;
        u0.q = *(const float4*)&W1s[s * 64 + kA];
        u1.q = *(const float4*)&W1s[s * 64 + kA + 4];
        u2.q = *(const float4*)&W1s[s * 64 + 32 + kA];
        u3.q = *(const float4*)&W1s[s * 64 + 36 + kA];
        w1f[s][0] = u0.h[0]; w1f[s][1] = u0.h[1];
        w1f[s][2] = u1.h[0]; w1f[s][3] = u1.h[1];
        w1f[s][4] = u2.h[0]; w1f[s][5] = u2.h[1];
        w1f[s][6] = u3.h[0]; w1f[s][7] = u3.h[1];
    }

    // ---- main loop: one 16-pair m-tile per wave-round, ZERO barriers ----
    #pragma clang loop unroll(disable)
    for (int r = 0; r < 8; ++r) {
        const int mtl = r * 4 + wv;
        if (mtl >= 31) break;                    // wave-uniform
        const int p = mtl * 16 + ml;
        const int i = sI[p], j = sJ[p];
        const int sw = (p >> 2) & 1;
        Q2 S0, S1;
        S0.q = *(const float4*)&sScal[p * 8 + (sw << 2)];        // td,pd,vd,rr
        S1.q = *(const float4*)&sScal[p * 8 + ((sw ^ 1) << 2)];  // ld,pr,gate,-
        const float sc[6] = {S0.q.x, S0.q.y, S0.q.z, S0.q.w, S1.q.x, S1.q.y};
        const float* Ar = &sAi[i * LDA];
        const float* Br = &sBj[j * LDA];

        // ks0 half: k = kA..kA+7 (W1s from registers)
        FragU fa0, fa1;
        {
            Q2 P0, P1, Q0, Q1;
            P0.q = *(const float4*)(Ar + kA);
            P1.q = *(const float4*)(Ar + kA + 4);
            Q0.q = *(const float4*)(Br + kA);
            Q1.q = *(const float4*)(Br + kA + 4);
            f2 v[4] = {P0.h[0] + Q0.h[0], P0.h[1] + Q0.h[1],
                       P1.h[0] + Q1.h[0], P1.h[1] + Q1.h[1]};
            #pragma unroll
            for (int s = 0; s < 6; ++s) {
                const f2 scs = splat2(sc[s]);
                #pragma unroll
                for (int c = 0; c < 4; ++c)
                    v[c] = pk_fma(scs, w1f[s][c], v[c]);
            }
            #pragma unroll
            for (int c = 0; c < 4; ++c) v[c] = gelu2(v[c]);
            fa0.u.x = pack_bf16_rne(v[0].x, v[0].y);
            fa0.u.y = pack_bf16_rne(v[1].x, v[1].y);
            fa0.u.z = pack_bf16_rne(v[2].x, v[2].y);
            fa0.u.w = pack_bf16_rne(v[3].x, v[3].y);
        }
        // ks1 half: k = 32+kA.. (W1s from registers)
        {
            Q2 P2, P3, Q2v, Q3;
            P2.q  = *(const float4*)(Ar + 32 + kA);
            P3.q  = *(const float4*)(Ar + 36 + kA);
            Q2v.q = *(const float4*)(Br + 32 + kA);
            Q3.q  = *(const float4*)(Br + 36 + kA);
            f2 y[4] = {P2.h[0] + Q2v.h[0], P2.h[1] + Q2v.h[1],
                       P3.h[0] + Q3.h[0],  P3.h[1] + Q3.h[1]};
            #pragma unroll
            for (int s = 0; s < 6; ++s) {
                const f2 scs = splat2(sc[s]);
                #pragma unroll
                for (int c = 0; c < 4; ++c)
                    y[c] = pk_fma(scs, w1f[s][4 + c], y[c]);
            }
            #pragma unroll
            for (int c = 0; c < 4; ++c) y[c] = gelu2(y[c]);
            fa1.u.x = pack_bf16_rne(y[0].x, y[0].y);
            fa1.u.y = pack_bf16_rne(y[1].x, y[1].y);
            fa1.u.z = pack_bf16_rne(y[2].x, y[2].y);
            fa1.u.w = pack_bf16_rne(y[3].x, y[3].y);
        }

        // h2 = h1 @ W2 on the matrix pipe
        v4f acc0 = {b2v0, b2v0, b2v0, b2v0};
        v4f acc1 = {b2v1, b2v1, b2v1, b2v1};
        acc0 = __builtin_amdgcn_mfma_f32_16x16x32_bf16(fa0.s, f00.s, acc0, 0, 0, 0);
        acc0 = __builtin_amdgcn_mfma_f32_16x16x32_bf16(fa1.s, f01.s, acc0, 0, 0, 0);
        acc1 = __builtin_amdgcn_mfma_f32_16x16x32_bf16(fa0.s, f10.s, acc1, 0, 0, 0);
        acc1 = __builtin_amdgcn_mfma_f32_16x16x32_bf16(fa1.s, f11.s, acc1, 0, 0, 0);

        // epilogue: pk gelu + W3 dot (row_ror reduce leaves sum in EVERY lane)
        // -> lane rsel=ml&3 picks its pair -> ONE sigmoid/gate per tile.
        float cres[4];
        #pragma unroll
        for (int rr = 0; rr < 4; ++rr) {
            const f2 g = gelu2(f2m(acc0[rr], acc1[rr]));
            cres[rr] = row_reduce16(fmaf(g.y, w3v1, g.x * w3v0));
        }
        const int rsel = ml & 3;     // constant-index ternary: no scratch
        const float cs = (rsel & 2) ? ((rsel & 1) ? cres[3] : cres[2])
                                    : ((rsel & 1) ? cres[1] : cres[0]);
        const int pe = mtl * 16 + ql * 4 + rsel;
        const int swe = (pe >> 2) & 1;
        const float gate = sScal[pe * 8 + ((swe ^ 1) << 2) + 2];
        const float fe = sigmoid_(cs + b3s) * gate;
        if (ml < 4) {
            const int pi = sI[pe], pj = sJ[pe];
            sAdj[pi * 32 + pj] = fe;
            sAdj[pj * 32 + pi] = fe;
        }
    }
    __syncthreads();   // barrier 3

    // ---- coalesced tile writeback ----
    float* dst = out + (size_t)b * 1024;
    for (int idx = t; idx < 1024; idx += 256) dst[idx] = sAdj[idx];
}

extern "C" void kernel_launch(void* const* d_in, const int* in_sizes, int n_in,
                              void* d_out, int out_size, void* d_ws, size_t ws_size,
                              hipStream_t stream) {
    const float* cel   = (const float*)d_in[0];
    const float* theta = (const float*)d_in[1];
    const float* phi   = (const float*)d_in[2];
    const float* vel   = (const float*)d_in[3];
    const float* rad   = (const float*)d_in[4];
    const float* lon   = (const float*)d_in[5];
    const float* W1    = (const float*)d_in[6];
    const float* b1    = (const float*)d_in[7];
    const float* W2    = (const float*)d_in[8];
    const float* b2    = (const float*)d_in[9];
    const float* W3    = (const float*)d_in[10];
    const float* b3    = (const float*)d_in[11];
    const float* pw    = (const float*)d_in[12];
    float* out = (float*)d_out;

    const int B = in_sizes[1] / NN;  // theta is (B,N)
    edge_kernel<<<B, 256, 0, stream>>>(cel, theta, phi, vel, rad, lon,
                                       W1, b1, W2, b2, W3, b3, pw, out);
}

// Round 10
// 237.489 us; speedup vs baseline: 1.1243x; 1.0054x over previous
//
#include <hip/hip_runtime.h>
#include <hip/hip_bf16.h>
#include <math.h>

#define SS 8
#define NN 32
#define DD 64
#define NP 496    // 32*31/2
#define LDAH 72   // padded row stride (f16 elems) for sAiH/sBjH; 144B, 16B-aligned

typedef short v8s __attribute__((ext_vector_type(8)));      // 8 bf16 (4 VGPRs)
typedef float v4f __attribute__((ext_vector_type(4)));      // MFMA C/D frag
typedef float f2  __attribute__((ext_vector_type(2)));      // packed fp32 pair
typedef _Float16 h8v __attribute__((ext_vector_type(8)));   // 8 f16 (4 VGPRs)

union FragU { uint4 u; v8s s; };
union Q2    { float4 q; f2 h[2]; };

static __device__ __forceinline__ f2 f2m(float a, float b) { f2 r; r.x = a; r.y = b; return r; }
static __device__ __forceinline__ f2 splat2(float s) { f2 r; r.x = s; r.y = s; return r; }
static __device__ __forceinline__ f2 pk_fma(f2 a, f2 b, f2 c) {
#if __has_builtin(__builtin_elementwise_fma)
    return __builtin_elementwise_fma(a, b, c);
#else
    return f2m(fmaf(a.x, b.x, c.x), fmaf(a.y, b.y, c.y));
#endif
}
static __device__ __forceinline__ h8v splat8h(float s) {
    const _Float16 h = (_Float16)s;
    h8v r = {h, h, h, h, h, h, h, h};
    return r;
}
static __device__ __forceinline__ h8v splat8hh(_Float16 h) {
    h8v r = {h, h, h, h, h, h, h, h};
    return r;
}

__device__ __forceinline__ float wrap_pi(float d) {
    return fmaf(-6.28318530717958647692f, rintf(d * 0.15915494309189533577f), d);
}
__device__ __forceinline__ float sigmoid_(float x) {
    return __builtin_amdgcn_rcpf(1.0f + __expf(-x));
}
// f32 packed GELU (epilogue only). A&S 7.1.26 rational, |eps|<=5e-4.
__device__ __forceinline__ f2 gelu2(f2 x) {
#if __has_builtin(__builtin_elementwise_max)
    f2 ax = __builtin_elementwise_max(x, -x);
#else
    f2 ax = f2m(fabsf(x.x), fabsf(x.y));
#endif
    f2 az = ax * splat2(0.70710678118654752440f);
    f2 d = pk_fma(splat2(0.078108f), az, splat2(0.000972f));
    d = pk_fma(d, az, splat2(0.230389f));
    d = pk_fma(d, az, splat2(0.278393f));
    d = pk_fma(d, az, splat2(1.0f));
    f2 t = f2m(__builtin_amdgcn_rcpf(d.x), __builtin_amdgcn_rcpf(d.y));
    f2 t2 = t * t;
    f2 a = ax * splat2(0.5f);
    f2 base = pk_fma(x, splat2(0.5f), a);
    f2 u = a * t2;
    return pk_fma(-u, t2, base);
}
// Packed-f16 GELU, same rational. v_pk_*_f16 is FULL-rate (2 elems / 2 cyc)
// vs v_pk_*_f32 at half-rate (157.3 TF fp32 peak = 1 FMA/lane/cyc) -> the h1
// pipeline's cycles halve at equal instruction count. Inf-flow is safe: huge
// |x| -> az^k inf -> d inf -> rcp 0 -> gelu = base (= x for x>0, 0 for x<0).
__device__ __forceinline__ h8v gelu8h(h8v x) {
    h8v ax = __builtin_elementwise_max(x, -x);
    h8v az = ax * splat8h(0.70710678118654752440f);
    h8v d = __builtin_elementwise_fma(splat8h(0.078108f), az, splat8h(0.000972f));
    d = __builtin_elementwise_fma(d, az, splat8h(0.230389f));
    d = __builtin_elementwise_fma(d, az, splat8h(0.278393f));
    d = __builtin_elementwise_fma(d, az, splat8h(1.0f));
    h8v t;
    #pragma unroll
    for (int k = 0; k < 8; ++k)
#if __has_builtin(__builtin_amdgcn_rcph)
        t[k] = __builtin_amdgcn_rcph(d[k]);
#else
        t[k] = (_Float16)__builtin_amdgcn_rcpf((float)d[k]);
#endif
    h8v t2 = t * t;
    h8v a = ax * splat8h(0.5f);
    h8v base = __builtin_elementwise_fma(x, splat8h(0.5f), a);
    h8v u = a * t2;
    return __builtin_elementwise_fma(-u, t2, base);
}
__device__ __forceinline__ unsigned int pack_bf16_rne(float x0, float x1) {
    union { __hip_bfloat162 h2; unsigned int u; } cv;
    float2 f; f.x = x0; f.y = x1;
    cv.h2 = __float22bfloat162_rn(f);
    return cv.u;
}
// residual-lo pack: bf16(x - f32(bf16_hi(x))) for a packed hi word.
__device__ __forceinline__ unsigned int res_pack(unsigned int hw, float x0, float x1) {
    const float f0 = __uint_as_float(hw << 16);
    const float f1 = __uint_as_float(hw & 0xFFFF0000u);
    return pack_bf16_rne(x0 - f0, x1 - f1);
}
// 16-lane DPP row-rotation butterfly sum (every lane ends with the row sum).
__device__ __forceinline__ float row_reduce16(float x) {
    int v;
    v = __builtin_amdgcn_update_dpp(0, __float_as_int(x), 0x128, 0xf, 0xf, false);
    x += __int_as_float(v);
    v = __builtin_amdgcn_update_dpp(0, __float_as_int(x), 0x124, 0xf, 0xf, false);
    x += __int_as_float(v);
    v = __builtin_amdgcn_update_dpp(0, __float_as_int(x), 0x122, 0xf, 0xf, false);
    x += __int_as_float(v);
    v = __builtin_amdgcn_update_dpp(0, __float_as_int(x), 0x121, 0xf, 0xf, false);
    x += __int_as_float(v);
    return x;
}
// W2 B-fragment in f16 (better than bf16: 5e-4 vs 4e-3 rel quantization).
__device__ __forceinline__ h8v build_w2_fragh(const float* __restrict__ W2,
                                              int kb, int col) {
    h8v r;
    #pragma unroll
    for (int k = 0; k < 8; ++k) r[k] = (_Float16)W2[(kb + k) * 32 + col];
    return r;
}

// History: R2: launch_bounds(256,4) caps VGPR at 64 -> scratch spill. R4:
// block=512 diverges post-timing (abandoned). R5/R7: +20 VGPR ILP pipelines
// -> occ 28->20%. R0/R3/R8: LDS 38-42KB all ~89.5us -- static resources
// exhausted. R9: phase A -> MFMA = 89.5 -> ~83us (VALU-work removal works).
// R10: the h1 pipeline (P+Q + rank-6 + gelu, ~150 pk_f32/round at HALF-rate
// 4cyc) moves to packed f16 (full-rate 2cyc): sAi/sBj stored f16, h2 MFMA
// switches to the f16 variant (kills the bf16 repack), ds_reads halve.
// rr (radius ratio, up to ~7e4) is clamped to 3e4 in the f16 splat only --
// f16-inf guard; output-invariant since those pairs' sigmoids saturate.
__global__ __launch_bounds__(256, 2) void edge_kernel(
    const float* __restrict__ cel,    // (B,S,N,D)
    const float* __restrict__ theta,  // (B,N)
    const float* __restrict__ phi,
    const float* __restrict__ vel,
    const float* __restrict__ rad,
    const float* __restrict__ lon,
    const float* __restrict__ W1,     // (134,64)
    const float* __restrict__ b1,     // (64)
    const float* __restrict__ W2,     // (64,32)
    const float* __restrict__ b2,     // (32)
    const float* __restrict__ W3,     // (32)
    const float* __restrict__ b3,     // (1)
    const float* __restrict__ pw,     // (6)
    float* __restrict__ out)          // (B,N,N)
{
    __shared__ __align__(16) _Float16 sAiH[NN * LDAH];  // fi@W1[0:64]+b1, f16
    __shared__ __align__(16) _Float16 sBjH[NN * LDAH];  // fj@W1[64:128], f16
    __shared__ float sAdj[1024];
    __shared__ __align__(16) float sScal[NP * 8];       // {td,pd,vd,rr}|{ld,pr,gate,-}
    __shared__ unsigned char sI[NP], sJ[NP];

    const int b = blockIdx.x;
    const int t = threadIdx.x;
    const int ml = t & 15;            // frag row-within-tile / C col
    const int ql = (t >> 4) & 3;      // frag k-quad / C row-quad
    const int wv = t >> 6;            // wave id
    const int kA = ql * 8;            // this lane's ks0 k-base

    // ---- W2 B-fragments (f16) straight from global ----
    h8v f00h = build_w2_fragh(W2, 0 * 32 + kA, 0 * 16 + ml);
    h8v f01h = build_w2_fragh(W2, 1 * 32 + kA, 0 * 16 + ml);
    h8v f10h = build_w2_fragh(W2, 0 * 32 + kA, 1 * 16 + ml);
    h8v f11h = build_w2_fragh(W2, 1 * 32 + kA, 1 * 16 + ml);
    const float b2v0 = b2[ml], b2v1 = b2[16 + ml];
    const float w3v0 = W3[ml], w3v1 = W3[16 + ml];
    const float b3s  = b3[0];

    // ---- staging ----
    if (t < 31) {  // triu pair table
        int off = t * 31 - (t * (t - 1)) / 2;
        for (int j = t + 1; j < 32; ++j) {
            sI[off] = (unsigned char)t;
            sJ[off] = (unsigned char)j;
            ++off;
        }
    }
    for (int idx = t; idx < 1024; idx += 256) sAdj[idx] = 0.0f;
    __syncthreads();   // barrier 1

    // ---- per-pair scalars + gate (f32, unchanged) ----
    for (int p = t; p < NP; p += 256) {
        const int i = sI[p], j = sJ[p];
        const float td = wrap_pi(theta[b * NN + i] - theta[b * NN + j]);
        const float pd = wrap_pi(phi[b * NN + i] - phi[b * NN + j]);
        const float vd = vel[b * NN + i] - vel[b * NN + j];
        const float rr = rad[b * NN + i] * __builtin_amdgcn_rcpf(rad[b * NN + j] + 1e-8f);
        const float ld = wrap_pi(lon[b * NN + i] - lon[b * NN + j]);
        const float pr = __cosf(td) * __cosf(pd);
        const float pf = fabsf(td) * pw[0] + fabsf(pd) * pw[1]
                       + fabsf(vd) * pw[2] + fabsf(rr - 1.0f) * pw[3]
                       + fabsf(ld) * pw[4] + fabsf(pr) * pw[5];
        const int sw = (p >> 2) & 1;   // chunk XOR-swizzle bit
        float4* c0 = (float4*)&sScal[p * 8 + (sw << 2)];
        float4* c1 = (float4*)&sScal[p * 8 + ((sw ^ 1) << 2)];
        *c0 = float4{td, pd, vd, rr};
        *c1 = float4{ld, pr, sigmoid_(pf), 0.0f};
    }

    // ---- phase A on the MATRIX pipe (R9, unchanged math): split-bf16 A x
    // bf16 W1, b1 in C-init. Output now stored to LDS as f16. ----
    {
        const int w4 = __builtin_amdgcn_readfirstlane(t >> 6);
        const int tg = w4 >> 1;
        const int mt = w4 & 1;
        const float* fbase = cel + ((size_t)b * SS + (SS - 1)) * (NN * DD);
        const float* Arow = fbase + (mt * 16 + ml) * 64;
        const float4 e0 = *(const float4*)(Arow + kA);
        const float4 e1 = *(const float4*)(Arow + kA + 4);
        const float4 e2 = *(const float4*)(Arow + 32 + kA);
        const float4 e3 = *(const float4*)(Arow + 36 + kA);
        FragU Ah0, Al0, Ah1, Al1;
        Ah0.u.x = pack_bf16_rne(e0.x, e0.y);
        Ah0.u.y = pack_bf16_rne(e0.z, e0.w);
        Ah0.u.z = pack_bf16_rne(e1.x, e1.y);
        Ah0.u.w = pack_bf16_rne(e1.z, e1.w);
        Al0.u.x = res_pack(Ah0.u.x, e0.x, e0.y);
        Al0.u.y = res_pack(Ah0.u.y, e0.z, e0.w);
        Al0.u.z = res_pack(Ah0.u.z, e1.x, e1.y);
        Al0.u.w = res_pack(Ah0.u.w, e1.z, e1.w);
        Ah1.u.x = pack_bf16_rne(e2.x, e2.y);
        Ah1.u.y = pack_bf16_rne(e2.z, e2.w);
        Ah1.u.z = pack_bf16_rne(e3.x, e3.y);
        Ah1.u.w = pack_bf16_rne(e3.z, e3.w);
        Al1.u.x = res_pack(Ah1.u.x, e2.x, e2.y);
        Al1.u.y = res_pack(Ah1.u.y, e2.z, e2.w);
        Al1.u.z = res_pack(Ah1.u.z, e3.x, e3.y);
        Al1.u.w = res_pack(Ah1.u.w, e3.z, e3.w);

        const float* WB = W1 + (tg * 64) * 64;
        _Float16* dstS = tg ? sBjH : sAiH;
        #pragma clang loop unroll(disable)   // serial nt: cap VGPR liveness
        for (int nt = 0; nt < 4; ++nt) {
            const int colb = nt * 16 + ml;
            const float* B0p = WB + kA * 64 + colb;
            const float* B1p = WB + (32 + kA) * 64 + colb;
            FragU B0, B1;
            B0.u.x = pack_bf16_rne(B0p[0],   B0p[64]);
            B0.u.y = pack_bf16_rne(B0p[128], B0p[192]);
            B0.u.z = pack_bf16_rne(B0p[256], B0p[320]);
            B0.u.w = pack_bf16_rne(B0p[384], B0p[448]);
            B1.u.x = pack_bf16_rne(B1p[0],   B1p[64]);
            B1.u.y = pack_bf16_rne(B1p[128], B1p[192]);
            B1.u.z = pack_bf16_rne(B1p[256], B1p[320]);
            B1.u.w = pack_bf16_rne(B1p[384], B1p[448]);
            const float cinit = tg ? 0.0f : b1[colb];
            v4f acc = {cinit, cinit, cinit, cinit};
            acc = __builtin_amdgcn_mfma_f32_16x16x32_bf16(Ah0.s, B0.s, acc, 0, 0, 0);
            acc = __builtin_amdgcn_mfma_f32_16x16x32_bf16(Al0.s, B0.s, acc, 0, 0, 0);
            acc = __builtin_amdgcn_mfma_f32_16x16x32_bf16(Ah1.s, B1.s, acc, 0, 0, 0);
            acc = __builtin_amdgcn_mfma_f32_16x16x32_bf16(Al1.s, B1.s, acc, 0, 0, 0);
            dstS[(mt * 16 + ql * 4 + 0) * LDAH + colb] = (_Float16)acc[0];
            dstS[(mt * 16 + ql * 4 + 1) * LDAH + colb] = (_Float16)acc[1];
            dstS[(mt * 16 + ql * 4 + 2) * LDAH + colb] = (_Float16)acc[2];
            dstS[(mt * 16 + ql * 4 + 3) * LDAH + colb] = (_Float16)acc[3];
        }
    }
    __syncthreads();   // barrier 2

    // ---- hoist W1s rows 128..133 for this lane, f16 (48 VGPR, was 96 f32) ----
    const float* W1s = W1 + 128 * 64;
    h8v w1fh[6][2];
    #pragma unroll
    for (int s = 0; s < 6; ++s) {
        const float4 u0 = *(const float4*)&W1s[s * 64 + kA];
        const float4 u1 = *(const float4*)&W1s[s * 64 + kA + 4];
        const float4 u2 = *(const float4*)&W1s[s * 64 + 32 + kA];
        const float4 u3 = *(const float4*)&W1s[s * 64 + 36 + kA];
        w1fh[s][0] = h8v{(_Float16)u0.x, (_Float16)u0.y, (_Float16)u0.z, (_Float16)u0.w,
                         (_Float16)u1.x, (_Float16)u1.y, (_Float16)u1.z, (_Float16)u1.w};
        w1fh[s][1] = h8v{(_Float16)u2.x, (_Float16)u2.y, (_Float16)u2.z, (_Float16)u2.w,
                         (_Float16)u3.x, (_Float16)u3.y, (_Float16)u3.z, (_Float16)u3.w};
    }

    // ---- main loop: one 16-pair m-tile per wave-round, ZERO barriers.
    //      h1 pipeline fully in packed f16; h2 MFMA = f16 variant. ----
    #pragma clang loop unroll(disable)
    for (int r = 0; r < 8; ++r) {
        const int mtl = r * 4 + wv;
        if (mtl >= 31) break;                    // wave-uniform
        const int p = mtl * 16 + ml;
        const int i = sI[p], j = sJ[p];
        const int sw = (p >> 2) & 1;
        Q2 S0, S1;
        S0.q = *(const float4*)&sScal[p * 8 + (sw << 2)];        // td,pd,vd,rr
        S1.q = *(const float4*)&sScal[p * 8 + ((sw ^ 1) << 2)];  // ld,pr,gate,-
        const _Float16 sch[6] = {
            (_Float16)S0.q.x, (_Float16)S0.q.y, (_Float16)S0.q.z,
            (_Float16)fminf(S0.q.w, 30000.0f),   // f16-inf guard on rr
            (_Float16)S1.q.x, (_Float16)S1.q.y};
        const _Float16* ArH = &sAiH[i * LDAH];
        const _Float16* BrH = &sBjH[j * LDAH];

        // ks0 half: cols kA..kA+7 (one b128 each; f16 = 8 cols / 16B)
        h8v v0;
        {
            const h8v P = *(const h8v*)(ArH + kA);
            const h8v Q = *(const h8v*)(BrH + kA);
            h8v v = P + Q;
            #pragma unroll
            for (int s = 0; s < 6; ++s)
                v = __builtin_elementwise_fma(splat8hh(sch[s]), w1fh[s][0], v);
            v0 = gelu8h(v);
        }
        // ks1 half: cols 32+kA..+7
        h8v v1;
        {
            const h8v P = *(const h8v*)(ArH + 32 + kA);
            const h8v Q = *(const h8v*)(BrH + 32 + kA);
            h8v y = P + Q;
            #pragma unroll
            for (int s = 0; s < 6; ++s)
                y = __builtin_elementwise_fma(splat8hh(sch[s]), w1fh[s][1], y);
            v1 = gelu8h(y);
        }

        // h2 = h1 @ W2 on the matrix pipe (f16 operands, no repack step)
        v4f acc0 = {b2v0, b2v0, b2v0, b2v0};
        v4f acc1 = {b2v1, b2v1, b2v1, b2v1};
        acc0 = __builtin_amdgcn_mfma_f32_16x16x32_f16(v0, f00h, acc0, 0, 0, 0);
        acc0 = __builtin_amdgcn_mfma_f32_16x16x32_f16(v1, f01h, acc0, 0, 0, 0);
        acc1 = __builtin_amdgcn_mfma_f32_16x16x32_f16(v0, f10h, acc1, 0, 0, 0);
        acc1 = __builtin_amdgcn_mfma_f32_16x16x32_f16(v1, f11h, acc1, 0, 0, 0);

        // epilogue (f32, unchanged): pk gelu + W3 dot + DPP row reduce
        float cres[4];
        #pragma unroll
        for (int rr2 = 0; rr2 < 4; ++rr2) {
            const f2 g = gelu2(f2m(acc0[rr2], acc1[rr2]));
            cres[rr2] = row_reduce16(fmaf(g.y, w3v1, g.x * w3v0));
        }
        const int rsel = ml & 3;
        const float cs = (rsel & 2) ? ((rsel & 1) ? cres[3] : cres[2])
                                    : ((rsel & 1) ? cres[1] : cres[0]);
        const int pe = mtl * 16 + ql * 4 + rsel;
        const int swe = (pe >> 2) & 1;
        const float gate = sScal[pe * 8 + ((swe ^ 1) << 2) + 2];
        const float fe = sigmoid_(cs + b3s) * gate;
        if (ml < 4) {
            const int pi = sI[pe], pj = sJ[pe];
            sAdj[pi * 32 + pj] = fe;
            sAdj[pj * 32 + pi] = fe;
        }
    }
    __syncthreads();   // barrier 3

    // ---- coalesced tile writeback ----
    float* dst = out + (size_t)b * 1024;
    for (int idx = t; idx < 1024; idx += 256) dst[idx] = sAdj[idx];
}

extern "C" void kernel_launch(void* const* d_in, const int* in_sizes, int n_in,
                              void* d_out, int out_size, void* d_ws, size_t ws_size,
                              hipStream_t stream) {
    const float* cel   = (const float*)d_in[0];
    const float* theta = (const float*)d_in[1];
    const float* phi   = (const float*)d_in[2];
    const float* vel   = (const float*)d_in[3];
    const float* rad   = (const float*)d_in[4];
    const float* lon   = (const float*)d_in[5];
    const float* W1    = (const float*)d_in[6];
    const float* b1    = (const float*)d_in[7];
    const float* W2    = (const float*)d_in[8];
    const float* b2    = (const float*)d_in[9];
    const float* W3    = (const float*)d_in[10];
    const float* b3    = (const float*)d_in[11];
    const float* pw    = (const float*)d_in[12];
    float* out = (float*)d_out;

    const int B = in_sizes[1] / NN;  // theta is (B,N)
    edge_kernel<<<B, 256, 0, stream>>>(cel, theta, phi, vel, rad, lon,
                                       W1, b1, W2, b2, W3, b3, pw, out);
}